// Round 7
// baseline (199.719 us; speedup 1.0000x reference)
//
#include <hip/hip_runtime.h>

typedef float f32x4 __attribute__((ext_vector_type(4)));
typedef short bf16x8 __attribute__((ext_vector_type(8)));

#define NB 8
#define NH 16
#define NSEQ 1024
#define NP 64
#define NKV 1088
#define NC 1024
#define NHD 64

__device__ __forceinline__ unsigned short f2bf(float f) {
  unsigned int u = __builtin_bit_cast(unsigned int, f);
  u += 0x7fffu + ((u >> 16) & 1u);  // RNE
  return (unsigned short)(u >> 16);
}

__device__ __forceinline__ void gload16(const void* g, void* l) {
  __builtin_amdgcn_global_load_lds((const __attribute__((address_space(1))) void*)g,
                                   (__attribute__((address_space(3))) void*)l, 16, 0, 0);
}

__device__ __forceinline__ f32x4 mfma16(bf16x8 a, bf16x8 b, f32x4 c) {
  return __builtin_amdgcn_mfma_f32_16x16x32_bf16(a, b, c, 0, 0, 0);
}

// ---------------- pack kernels ----------------
__global__ void pack_all(const float* __restrict__ x, const float* __restrict__ wq,
                         const float* __restrict__ wp, unsigned short* __restrict__ xd,
                         unsigned short* __restrict__ wqd, unsigned short* __restrict__ wpd) {
  int i = blockIdx.x * 256 + threadIdx.x;  // 3145728 float4s total
  const float* s;
  unsigned short* d;
  int off;
  if (i < 2097152) { s = x; d = xd; off = i; }
  else if (i < 2883584) { s = wq; d = wqd; off = i - 2097152; }
  else { s = wp; d = wpd; off = i - 2883584; }
  float4 v = ((const float4*)s)[off];
  ushort4 o;
  o.x = f2bf(v.x); o.y = f2bf(v.y); o.z = f2bf(v.z); o.w = f2bf(v.w);
  ((ushort4*)d)[off] = o;
}

// prompt [B,2,P,H,hd] f32 -> Kg prefix [B,H,p<64,hd]*a (bf16), Vt prefix [B,H,hd,p<64]*a (bf16)
__global__ void prefix_pack(const float* __restrict__ prompt, unsigned short* __restrict__ Kg,
                            unsigned short* __restrict__ Vt, const float* __restrict__ alpha) {
  int i = blockIdx.x * 256 + threadIdx.x;  // 131072 total
  float a = alpha[0];
  int d4 = i & 15, p = (i >> 4) & 63, h = (i >> 10) & 15, b = i >> 14;
  const float4 kv = *(const float4*)(prompt + ((((size_t)(b * 2 + 0) * NP + p) * NH + h) * NHD + d4 * 4));
  ushort4 ko;
  ko.x = f2bf(kv.x * a); ko.y = f2bf(kv.y * a); ko.z = f2bf(kv.z * a); ko.w = f2bf(kv.w * a);
  *(ushort4*)(Kg + (((size_t)(b * NH + h) * NKV + p) * NHD + d4 * 4)) = ko;
  const float4 vv = *(const float4*)(prompt + ((((size_t)(b * 2 + 1) * NP + p) * NH + h) * NHD + d4 * 4));
  size_t vbase = ((size_t)(b * NH + h) * NHD + d4 * 4) * NKV + p;
  Vt[vbase]            = f2bf(vv.x * a);
  Vt[vbase + NKV]      = f2bf(vv.y * a);
  Vt[vbase + 2 * NKV]  = f2bf(vv.z * a);
  Vt[vbase + 3 * NKV]  = f2bf(vv.w * a);
}

// ---------------- QKV GEMM: 256x256 tile, 4-phase/K-tile, 1 barrier/phase ----------------
// 512 thr = 8 waves (2M x 4N; wave out 128x64 as 2x2 quadrants of 64x32).
// LDS 128KB: A[par][half][128x64], B[par][half][128x64].
// Per K-tile kt (buffer parity kt&1), phases:
//  ph0: ds_read a0,b0 (12 b128);                MFMA q(0,0); lgkm0; barrier
//  ph1: ds_read b1 (4); stage A0(kt+2);         MFMA q(0,1); lgkm0; barrier
//  ph2: ds_read a1 (8); stage B0,B1(kt+2);      MFMA q(1,0); lgkm0; barrier
//  ph3:                 stage A1(kt+2);         MFMA q(1,1); vmcnt(8); barrier
// WAR: each staged half-X(kt+2) issues >= one lgkm0+barrier after kt's last
// ds_read of half-X. RAW: vmcnt(8) at end of kt leaves kt+2's 8 loads in
// flight, forces kt+1's 8 landed. Never drains mid-loop. No sched_barrier
// (m141), no pointer-aliased frags (rule #20), setprio on MFMA (T5).
__global__ __launch_bounds__(512, 2)
void gemm_qkv(const unsigned short* __restrict__ A, const unsigned short* __restrict__ Bw,
              unsigned short* __restrict__ Qg, unsigned short* __restrict__ Kg,
              unsigned short* __restrict__ Vt,
              const float* __restrict__ alphap, const float* __restrict__ halfp) {
  const int K = 1024, NT = 16;
  __shared__ __align__(16) unsigned short lds[65536];  // bytes: A [0,65536), B [65536,131072)
  const int tid = threadIdx.x, lane = tid & 63, wv = tid >> 6;
  const int wm = wv >> 2, wn = wv & 3;
  const int lg = lane >> 4, lr = lane & 15;
  // XCD swizzle: 48 blocks/XCD, bx-outer -> per-XCD 4 A-stripes + 12 B-panels (FETCH 59MB, r5-verified)
  const int s = (blockIdx.x & 7) * 48 + (blockIdx.x >> 3);
  const int bx = s / 12, by = s % 12;

  // staging: half-tile = 128x64 bf16 = 1024 chunks of 16B; thread owns chunks tid, tid+512
  const int c0 = tid, c1 = tid + 512;
  const int r0 = c0 >> 3, g0 = (c0 & 7) ^ (r0 & 7);
  const int r1 = c1 >> 3, g1 = (c1 & 7) ^ (r1 & 7);
  const unsigned short* AgH[2][2];
  const unsigned short* BgH[2][2];
#pragma unroll
  for (int hf = 0; hf < 2; ++hf) {
    AgH[hf][0] = A + (size_t)(bx * 256 + hf * 128 + r0) * K + g0 * 8;
    AgH[hf][1] = A + (size_t)(bx * 256 + hf * 128 + r1) * K + g1 * 8;
    BgH[hf][0] = Bw + (size_t)(by * 256 + hf * 128 + r0) * K + g0 * 8;
    BgH[hf][1] = Bw + (size_t)(by * 256 + hf * 128 + r1) * K + g1 * 8;
  }
  const int o0 = c0 * 16, o1 = c1 * 16;  // byte offsets within a half-slot

#define STG_A(hf, kt)                                                          \
  do {                                                                         \
    char* base = (char*)lds + ((kt) & 1) * 32768 + (hf) * 16384;               \
    gload16(AgH[hf][0] + (size_t)(kt) * 64, base + o0);                        \
    gload16(AgH[hf][1] + (size_t)(kt) * 64, base + o1);                        \
  } while (0)
#define STG_B(hf, kt)                                                          \
  do {                                                                         \
    char* base = (char*)lds + 65536 + ((kt) & 1) * 32768 + (hf) * 16384;       \
    gload16(BgH[hf][0] + (size_t)(kt) * 64, base + o0);                        \
    gload16(BgH[hf][1] + (size_t)(kt) * 64, base + o1);                        \
  } while (0)

  f32x4 acc00[4][2] = {}, acc01[4][2] = {}, acc10[4][2] = {}, acc11[4][2] = {};
  const int pos0 = lg ^ (lr & 7), pos1 = (4 + lg) ^ (lr & 7);

  // prologue: kt0 + kt1 fully staged; vmcnt(8) -> kt0 landed, kt1 in flight
  STG_A(0, 0); STG_B(0, 0); STG_B(1, 0); STG_A(1, 0);
  STG_A(0, 1); STG_B(0, 1); STG_B(1, 1); STG_A(1, 1);
  asm volatile("s_waitcnt vmcnt(8)" ::: "memory");
  __builtin_amdgcn_s_barrier();
  asm volatile("" ::: "memory");

  for (int kt = 0; kt < NT; ++kt) {
    const int par = kt & 1;
    const unsigned short* Ap = lds + par * 16384;
    const unsigned short* Bp = lds + 32768 + par * 16384;
    bf16x8 a0[4][2], a1[4][2], b0[2][2], b1[2][2];

    // ---- phase 0: read a0 (A half0, 8) + b0 (B half0, 4); MFMA q(0,0)
#pragma unroll
    for (int mf = 0; mf < 4; ++mf) {
      const int ro = (wm * 64 + mf * 16 + lr) * 64;
      a0[mf][0] = *(const bf16x8*)(Ap + ro + pos0 * 8);
      a0[mf][1] = *(const bf16x8*)(Ap + ro + pos1 * 8);
    }
#pragma unroll
    for (int nf = 0; nf < 2; ++nf) {
      const int ro = (wn * 32 + nf * 16 + lr) * 64;
      b0[nf][0] = *(const bf16x8*)(Bp + ro + pos0 * 8);
      b0[nf][1] = *(const bf16x8*)(Bp + ro + pos1 * 8);
    }
    __builtin_amdgcn_s_setprio(1);
#pragma unroll
    for (int mf = 0; mf < 4; ++mf)
#pragma unroll
      for (int nf = 0; nf < 2; ++nf)
#pragma unroll
        for (int kk = 0; kk < 2; ++kk)
          acc00[mf][nf] = mfma16(a0[mf][kk], b0[nf][kk], acc00[mf][nf]);
    __builtin_amdgcn_s_setprio(0);
    asm volatile("s_waitcnt lgkmcnt(0)" ::: "memory");
    __builtin_amdgcn_s_barrier();
    asm volatile("" ::: "memory");

    // ---- phase 1: read b1 (B half1, 4); stage A0(kt+2); MFMA q(0,1)
#pragma unroll
    for (int nf = 0; nf < 2; ++nf) {
      const int ro = (wn * 32 + nf * 16 + lr) * 64;
      b1[nf][0] = *(const bf16x8*)(Bp + 8192 + ro + pos0 * 8);
      b1[nf][1] = *(const bf16x8*)(Bp + 8192 + ro + pos1 * 8);
    }
    if (kt + 2 < NT) STG_A(0, kt + 2);
    __builtin_amdgcn_s_setprio(1);
#pragma unroll
    for (int mf = 0; mf < 4; ++mf)
#pragma unroll
      for (int nf = 0; nf < 2; ++nf)
#pragma unroll
        for (int kk = 0; kk < 2; ++kk)
          acc01[mf][nf] = mfma16(a0[mf][kk], b1[nf][kk], acc01[mf][nf]);
    __builtin_amdgcn_s_setprio(0);
    asm volatile("s_waitcnt lgkmcnt(0)" ::: "memory");
    __builtin_amdgcn_s_barrier();
    asm volatile("" ::: "memory");

    // ---- phase 2: read a1 (A half1, 8); stage B0,B1(kt+2); MFMA q(1,0)
#pragma unroll
    for (int mf = 0; mf < 4; ++mf) {
      const int ro = (wm * 64 + mf * 16 + lr) * 64;
      a1[mf][0] = *(const bf16x8*)(Ap + 8192 + ro + pos0 * 8);
      a1[mf][1] = *(const bf16x8*)(Ap + 8192 + ro + pos1 * 8);
    }
    if (kt + 2 < NT) { STG_B(0, kt + 2); STG_B(1, kt + 2); }
    __builtin_amdgcn_s_setprio(1);
#pragma unroll
    for (int mf = 0; mf < 4; ++mf)
#pragma unroll
      for (int nf = 0; nf < 2; ++nf)
#pragma unroll
        for (int kk = 0; kk < 2; ++kk)
          acc10[mf][nf] = mfma16(a1[mf][kk], b0[nf][kk], acc10[mf][nf]);
    __builtin_amdgcn_s_setprio(0);
    asm volatile("s_waitcnt lgkmcnt(0)" ::: "memory");
    __builtin_amdgcn_s_barrier();
    asm volatile("" ::: "memory");

    // ---- phase 3: stage A1(kt+2); MFMA q(1,1); counted vmcnt; barrier
    if (kt + 2 < NT) STG_A(1, kt + 2);
    __builtin_amdgcn_s_setprio(1);
#pragma unroll
    for (int mf = 0; mf < 4; ++mf)
#pragma unroll
      for (int nf = 0; nf < 2; ++nf)
#pragma unroll
        for (int kk = 0; kk < 2; ++kk)
          acc11[mf][nf] = mfma16(a1[mf][kk], b1[nf][kk], acc11[mf][nf]);
    __builtin_amdgcn_s_setprio(0);
    if (kt < NT - 2) asm volatile("s_waitcnt vmcnt(8)" ::: "memory");
    else             asm volatile("s_waitcnt vmcnt(0)" ::: "memory");
    __builtin_amdgcn_s_barrier();
    asm volatile("" ::: "memory");
  }
#undef STG_A
#undef STG_B

  // epilogue: scatter to Q / K(+64) / V^T(+64)
  const int slot = by >> 2;            // 0=q 1=k 2=v (256-col tiles never straddle)
  const int csIn = (by & 3) * 256;
  const float sc = (slot == 0) ? 0.18033688011112042f : (alphap[0] * halfp[0]);
#pragma unroll
  for (int qm = 0; qm < 2; ++qm)
#pragma unroll
    for (int qn = 0; qn < 2; ++qn)
#pragma unroll
      for (int mf = 0; mf < 4; ++mf) {
        const int grow0 = bx * 256 + qm * 128 + wm * 64 + mf * 16 + lg * 4;
#pragma unroll
        for (int nf = 0; nf < 2; ++nf) {
          const int gcol = csIn + qn * 128 + wn * 32 + nf * 16 + lr;
          const int h = gcol >> 6, d = gcol & 63;
#pragma unroll
          for (int j = 0; j < 4; ++j) {
            const int grow = grow0 + j;
            const int b = grow >> 10, nn = grow & 1023;
            const f32x4* accp = qm == 0 ? (qn == 0 ? &acc00[mf][nf] : &acc01[mf][nf])
                                        : (qn == 0 ? &acc10[mf][nf] : &acc11[mf][nf]);
            const unsigned short u = f2bf((*accp)[j] * sc);
            if (slot == 0)      Qg[(((size_t)b * NH + h) * NSEQ + nn) * NHD + d] = u;
            else if (slot == 1) Kg[(((size_t)b * NH + h) * NKV + NP + nn) * NHD + d] = u;
            else                Vt[(((size_t)b * NH + h) * NHD + d) * NKV + NP + nn] = u;
          }
        }
      }
}

// ---------------- proj GEMM (r3-proven 128x128, BK=64 dbuf, counted vmcnt) ----------------
__global__ __launch_bounds__(256, 2)
void gemm_proj(const unsigned short* __restrict__ A, const unsigned short* __restrict__ Bw,
               float* __restrict__ Cout, const float* __restrict__ bias) {
  const int K = 1024;
  __shared__ __align__(16) unsigned short ldsA[2][128 * 64];
  __shared__ __align__(16) unsigned short ldsB[2][128 * 64];
  const int tid = threadIdx.x, lane = tid & 63, wv = tid >> 6;
  const int wr = wv >> 1, wc = wv & 1;
  const int lg = lane >> 4, lr = lane & 15;
  const int bx = blockIdx.x, by = blockIdx.y;

  f32x4 acc[4][4] = {};

  const unsigned short* Ag[4];
  const unsigned short* Bg[4];
  int ldof[4];
#pragma unroll
  for (int i = 0; i < 4; ++i) {
    const int c = tid + 256 * i;
    const int row = c >> 3;
    const int gch = (c & 7) ^ (row & 7);
    Ag[i] = A + (size_t)(bx * 128 + row) * K + gch * 8;
    Bg[i] = Bw + (size_t)(by * 128 + row) * K + gch * 8;
    ldof[i] = c * 16;
  }

#define GSTAGE(t, bsel)                                                        \
  do {                                                                         \
    char* lA = (char*)&ldsA[bsel][0];                                          \
    char* lB = (char*)&ldsB[bsel][0];                                          \
    _Pragma("unroll") for (int i = 0; i < 4; ++i)                              \
        gload16(Ag[i] + (size_t)(t) * 64, lA + ldof[i]);                       \
    _Pragma("unroll") for (int i = 0; i < 4; ++i)                              \
        gload16(Bg[i] + (size_t)(t) * 64, lB + ldof[i]);                       \
  } while (0)

  const int nst = K >> 6;  // 16
  int buf = 0;
  GSTAGE(0, 0);
  for (int t = 0; t < nst; ++t) {
    if (t < nst - 1) {
      GSTAGE(t + 1, buf ^ 1);
      asm volatile("s_waitcnt vmcnt(8)" ::: "memory");
    } else {
      asm volatile("s_waitcnt vmcnt(0)" ::: "memory");
    }
    __builtin_amdgcn_s_barrier();
    asm volatile("" ::: "memory");

#pragma unroll
    for (int kk = 0; kk < 2; ++kk) {
      bf16x8 af[4], bfm[4];
#pragma unroll
      for (int m = 0; m < 4; ++m) {
        const int row = wr * 64 + m * 16 + lr;
        const int pos = (kk * 4 + lg) ^ (row & 7);
        af[m] = *(const bf16x8*)(&ldsA[buf][0] + row * 64 + pos * 8);
      }
#pragma unroll
      for (int n = 0; n < 4; ++n) {
        const int row = wc * 64 + n * 16 + lr;
        const int pos = (kk * 4 + lg) ^ (row & 7);
        bfm[n] = *(const bf16x8*)(&ldsB[buf][0] + row * 64 + pos * 8);
      }
      __builtin_amdgcn_s_setprio(1);
#pragma unroll
      for (int m = 0; m < 4; ++m)
#pragma unroll
        for (int n = 0; n < 4; ++n)
          acc[m][n] = mfma16(af[m], bfm[n], acc[m][n]);
      __builtin_amdgcn_s_setprio(0);
    }

    asm volatile("s_waitcnt lgkmcnt(0)" ::: "memory");
    __builtin_amdgcn_s_barrier();
    asm volatile("" ::: "memory");
    buf ^= 1;
  }
#undef GSTAGE

#pragma unroll
  for (int m = 0; m < 4; ++m) {
    const int grow0 = bx * 128 + wr * 64 + m * 16 + lg * 4;
#pragma unroll
    for (int n = 0; n < 4; ++n) {
      const int gcol = by * 128 + wc * 64 + n * 16 + lr;
      const float bb = bias[gcol];
#pragma unroll
      for (int j = 0; j < 4; ++j)
        Cout[(size_t)(grow0 + j) * NC + gcol] = acc[m][n][j] + bb;
    }
  }
}

// ---------------- flash attention (r3-proven: QBLK=128, 4 waves, swapped QK^T) ----------------
__global__ __launch_bounds__(256, 3)
void attn_fwd(const unsigned short* __restrict__ Qg, const unsigned short* __restrict__ Kg,
              const unsigned short* __restrict__ Vt, unsigned short* __restrict__ Oat) {
  __shared__ __align__(16) unsigned short Klds[2][64 * 64];
  __shared__ __align__(16) unsigned short Vlds[2][64 * 64];
  __shared__ __align__(16) unsigned short Plds[4 * 32 * 64];
  const int tid = threadIdx.x, lane = tid & 63, wv = tid >> 6;
  const int bh = blockIdx.x & 127;
  const int q0 = (blockIdx.x >> 7) * 128;
  const int lg = lane >> 4, lr = lane & 15;

  bf16x8 bq[2][2];
#pragma unroll
  for (int nq = 0; nq < 2; ++nq)
#pragma unroll
    for (int kk = 0; kk < 2; ++kk)
      bq[nq][kk] = *(const bf16x8*)(Qg + ((size_t)bh * NSEQ + q0 + wv * 32 + nq * 16 + lr) * NHD + kk * 32 + lg * 8);

  f32x4 oac[2][4] = {};
  float mrun[2] = {-1e30f, -1e30f};
  float lrun[2] = {0.f, 0.f};

  const int kr0 = tid >> 3, kc = tid & 7;
  const int sw = kc ^ (kr0 & 7);
  const unsigned short* Kgp = Kg + ((size_t)bh * NKV + kr0) * NHD + sw * 8;
  const unsigned short* Vgp = Vt + ((size_t)bh * NHD + kr0) * NKV + sw * 8;
  unsigned short* Pw = Plds + wv * 2048;

#define STAGE(t, bsel)                                                      \
  do {                                                                      \
    unsigned short* kb = &Klds[bsel][0] + wv * 512;                         \
    unsigned short* vb = &Vlds[bsel][0] + wv * 512;                         \
    gload16(Kgp + (size_t)(t) * 4096, kb);                                  \
    gload16(Kgp + (size_t)(t) * 4096 + 32 * NHD, kb + 2048);                \
    gload16(Vgp + (size_t)(t) * 64, vb);                                    \
    gload16(Vgp + (size_t)(t) * 64 + (size_t)32 * NKV, vb + 2048);          \
  } while (0)

  STAGE(0, 0);
  asm volatile("s_waitcnt vmcnt(0)" ::: "memory");
  __builtin_amdgcn_s_barrier();

  for (int t = 0; t < 17; ++t) {
    const int b = t & 1;
    if (t < 16) STAGE(t + 1, b ^ 1);

    f32x4 sa[4][2] = {};
    __builtin_amdgcn_s_setprio(1);
#pragma unroll
    for (int kk = 0; kk < 2; ++kk) {
      bf16x8 ak[4];
#pragma unroll
      for (int mk = 0; mk < 4; ++mk) {
        const int row = mk * 16 + lr;
        const int cc = (kk * 4 + lg) ^ (row & 7);
        ak[mk] = *(const bf16x8*)(&Klds[b][0] + row * 64 + cc * 8);
      }
#pragma unroll
      for (int mk = 0; mk < 4; ++mk)
#pragma unroll
        for (int nq = 0; nq < 2; ++nq)
          sa[mk][nq] = mfma16(ak[mk], bq[nq][kk], sa[mk][nq]);
    }
    __builtin_amdgcn_s_setprio(0);

    float tmx[2];
#pragma unroll
    for (int nq = 0; nq < 2; ++nq) {
      f32x4 m4 = sa[0][nq];
#pragma unroll
      for (int mk = 1; mk < 4; ++mk)
#pragma unroll
        for (int j = 0; j < 4; ++j) m4[j] = fmaxf(m4[j], sa[mk][nq][j]);
      float tm = fmaxf(fmaxf(m4[0], m4[1]), fmaxf(m4[2], m4[3]));
      tm = fmaxf(tm, __shfl_xor(tm, 16));
      tm = fmaxf(tm, __shfl_xor(tm, 32));
      tmx[nq] = tm;
    }
    const bool upd = !__all((tmx[0] <= mrun[0] + 8.f) && (tmx[1] <= mrun[1] + 8.f));
    if (upd) {
      const float nm0 = fmaxf(mrun[0], tmx[0]);
      const float nm1 = fmaxf(mrun[1], tmx[1]);
      const float e0 = __builtin_amdgcn_exp2f(mrun[0] - nm0);
      const float e1 = __builtin_amdgcn_exp2f(mrun[1] - nm1);
      mrun[0] = nm0; mrun[1] = nm1;
      lrun[0] *= e0; lrun[1] *= e1;
#pragma unroll
      for (int m = 0; m < 2; ++m)
#pragma unroll
        for (int j = 0; j < 4; ++j) {
          const float fe = __shfl(m ? e1 : e0, lg * 4 + j, 16);
#pragma unroll
          for (int df = 0; df < 4; ++df) oac[m][df][j] *= fe;
        }
    }
#pragma unroll
    for (int nq = 0; nq < 2; ++nq) {
#pragma unroll
      for (int mk = 0; mk < 4; ++mk)
#pragma unroll
        for (int j = 0; j < 4; ++j)
          sa[mk][nq][j] = __builtin_amdgcn_exp2f(sa[mk][nq][j] - mrun[nq]);
      f32x4 s4 = sa[0][nq];
#pragma unroll
      for (int mk = 1; mk < 4; ++mk)
#pragma unroll
        for (int j = 0; j < 4; ++j) s4[j] += sa[mk][nq][j];
      float s = (s4[0] + s4[1]) + (s4[2] + s4[3]);
      s += __shfl_xor(s, 16);
      s += __shfl_xor(s, 32);
      lrun[nq] += s;
      const int q = nq * 16 + lr;
#pragma unroll
      for (int mk = 0; mk < 4; ++mk) {
        const int c = mk * 2 + (lg >> 1);
        uint2 uu;
        uu.x = (unsigned)f2bf(sa[mk][nq][0]) | ((unsigned)f2bf(sa[mk][nq][1]) << 16);
        uu.y = (unsigned)f2bf(sa[mk][nq][2]) | ((unsigned)f2bf(sa[mk][nq][3]) << 16);
        *(uint2*)(Pw + q * 64 + ((c ^ (q & 7)) << 3) + (lg & 1) * 4) = uu;
      }
    }

    __builtin_amdgcn_s_setprio(1);
#pragma unroll
    for (int kk = 0; kk < 2; ++kk) {
      bf16x8 bv[4], ap[2];
#pragma unroll
      for (int df = 0; df < 4; ++df) {
        const int d = df * 16 + lr;
        const int cc = (kk * 4 + lg) ^ (d & 7);
        bv[df] = *(const bf16x8*)(&Vlds[b][0] + d * 64 + cc * 8);
      }
#pragma unroll
      for (int m = 0; m < 2; ++m) {
        const int q = m * 16 + lr;
        const int pos = (kk * 4 + lg) ^ (q & 7);
        ap[m] = *(const bf16x8*)(Pw + q * 64 + pos * 8);
      }
#pragma unroll
      for (int m = 0; m < 2; ++m)
#pragma unroll
        for (int df = 0; df < 4; ++df)
          oac[m][df] = mfma16(ap[m], bv[df], oac[m][df]);
    }
    __builtin_amdgcn_s_setprio(0);

    asm volatile("s_waitcnt vmcnt(0)" ::: "memory");
    __builtin_amdgcn_s_barrier();
  }
#undef STAGE

  const int bidx = bh >> 4, h = bh & 15;
  const float l0 = 1.f / lrun[0], l1 = 1.f / lrun[1];
#pragma unroll
  for (int m = 0; m < 2; ++m) {
#pragma unroll
    for (int j = 0; j < 4; ++j) {
      const float fi = __shfl(m ? l1 : l0, lg * 4 + j, 16);
      const int row = q0 + wv * 32 + m * 16 + lg * 4 + j;
#pragma unroll
      for (int df = 0; df < 4; ++df) {
        const int col = h * 64 + df * 16 + lr;
        Oat[((size_t)bidx * NSEQ + row) * NC + col] = f2bf(oac[m][df][j] * fi);
      }
    }
  }
}

// ---------------- launch ----------------
extern "C" void kernel_launch(void* const* d_in, const int* in_sizes, int n_in,
                              void* d_out, int out_size, void* d_ws, size_t ws_size,
                              hipStream_t stream) {
  const float* x      = (const float*)d_in[0];
  const float* prompt = (const float*)d_in[1];
  const float* alpha  = (const float*)d_in[2];
  const float* halfa  = (const float*)d_in[3];
  const float* Wqkv   = (const float*)d_in[4];
  const float* Wproj  = (const float*)d_in[5];
  const float* bproj  = (const float*)d_in[6];
  float* out = (float*)d_out;

  unsigned short* ws    = (unsigned short*)d_ws;
  unsigned short* x_bf  = ws;
  unsigned short* w_bf  = x_bf + (size_t)8192 * 1024;
  unsigned short* wp_bf = w_bf + (size_t)3072 * 1024;
  unsigned short* Qg    = wp_bf + (size_t)1024 * 1024;
  unsigned short* Kg    = Qg + (size_t)NB * NH * NSEQ * NHD;
  unsigned short* Vt    = Kg + (size_t)NB * NH * NKV * NHD;
  unsigned short* Oat   = Vt + (size_t)NB * NH * NKV * NHD;

  pack_all<<<12288, 256, 0, stream>>>(x, Wqkv, Wproj, x_bf, w_bf, wp_bf);
  prefix_pack<<<512, 256, 0, stream>>>(prompt, Kg, Vt, alpha);

  // QKV: M=8192 N=3072 -> 32 x 12 = 384 blocks of 256^2
  gemm_qkv<<<384, 512, 0, stream>>>(x_bf, w_bf, Qg, Kg, Vt, alpha, halfa);
  attn_fwd<<<1024, 256, 0, stream>>>(Qg, Kg, Vt, Oat);
  // proj: M=8192 N=1024 -> 64 x 8 of 128^2
  gemm_proj<<<dim3(64, 8), 256, 0, stream>>>(Oat, wp_bf, out, bproj);
}

// Round 8
// 198.836 us; speedup vs baseline: 1.0044x; 1.0044x over previous
//
#include <hip/hip_runtime.h>

typedef float f32x4 __attribute__((ext_vector_type(4)));
typedef short bf16x8 __attribute__((ext_vector_type(8)));

#define NB 8
#define NH 16
#define NSEQ 1024
#define NP 64
#define NKV 1088
#define NC 1024
#define NHD 64

__device__ __forceinline__ unsigned short f2bf(float f) {
  unsigned int u = __builtin_bit_cast(unsigned int, f);
  u += 0x7fffu + ((u >> 16) & 1u);  // RNE
  return (unsigned short)(u >> 16);
}

__device__ __forceinline__ void gload16(const void* g, void* l) {
  __builtin_amdgcn_global_load_lds((const __attribute__((address_space(1))) void*)g,
                                   (__attribute__((address_space(3))) void*)l, 16, 0, 0);
}

__device__ __forceinline__ f32x4 mfma16(bf16x8 a, bf16x8 b, f32x4 c) {
  return __builtin_amdgcn_mfma_f32_16x16x32_bf16(a, b, c, 0, 0, 0);
}

// ---------------- pack kernels ----------------
__global__ void pack_all(const float* __restrict__ x, const float* __restrict__ wq,
                         const float* __restrict__ wp, unsigned short* __restrict__ xd,
                         unsigned short* __restrict__ wqd, unsigned short* __restrict__ wpd) {
  int i = blockIdx.x * 256 + threadIdx.x;  // 3145728 float4s total
  const float* s;
  unsigned short* d;
  int off;
  if (i < 2097152) { s = x; d = xd; off = i; }
  else if (i < 2883584) { s = wq; d = wqd; off = i - 2097152; }
  else { s = wp; d = wpd; off = i - 2883584; }
  float4 v = ((const float4*)s)[off];
  ushort4 o;
  o.x = f2bf(v.x); o.y = f2bf(v.y); o.z = f2bf(v.z); o.w = f2bf(v.w);
  ((ushort4*)d)[off] = o;
}

// prompt [B,2,P,H,hd] f32 -> Kg prefix [B,H,p<64,hd]*a (bf16), Vt prefix [B,H,hd,p<64]*a (bf16)
__global__ void prefix_pack(const float* __restrict__ prompt, unsigned short* __restrict__ Kg,
                            unsigned short* __restrict__ Vt, const float* __restrict__ alpha) {
  int i = blockIdx.x * 256 + threadIdx.x;  // 131072 total
  float a = alpha[0];
  int d4 = i & 15, p = (i >> 4) & 63, h = (i >> 10) & 15, b = i >> 14;
  const float4 kv = *(const float4*)(prompt + ((((size_t)(b * 2 + 0) * NP + p) * NH + h) * NHD + d4 * 4));
  ushort4 ko;
  ko.x = f2bf(kv.x * a); ko.y = f2bf(kv.y * a); ko.z = f2bf(kv.z * a); ko.w = f2bf(kv.w * a);
  *(ushort4*)(Kg + (((size_t)(b * NH + h) * NKV + p) * NHD + d4 * 4)) = ko;
  const float4 vv = *(const float4*)(prompt + ((((size_t)(b * 2 + 1) * NP + p) * NH + h) * NHD + d4 * 4));
  size_t vbase = ((size_t)(b * NH + h) * NHD + d4 * 4) * NKV + p;
  Vt[vbase]            = f2bf(vv.x * a);
  Vt[vbase + NKV]      = f2bf(vv.y * a);
  Vt[vbase + 2 * NKV]  = f2bf(vv.z * a);
  Vt[vbase + 3 * NKV]  = f2bf(vv.w * a);
}

// ---------------- QKV GEMM: 256x256, m201-style 4-phase, half-tile vmcnt ledger ----------
// 512 thr = 8 waves (2M x 4N interleaved: wave rows {wm*64..+63} u {128+wm*64..+63},
// cols {wn*32..+31} u {128+wn*32..+31}) so quadrant q(mq,nq) <-> tile half (mq A, nq B)
// for ALL waves. LDS 128KB dbuf. Per kt, 4 phases (one C-quadrant each):
//  ph0: read A-h0(8)+B-h0(4); stage A0(kt+1); [lgkm8]; bar; lgkm0; 16 MFMA; vmcnt4; bar
//  ph1: read B-h1(4);         stage B0(kt+1);          bar; lgkm0; 16 MFMA; vmcnt4; bar
//  ph2: read A-h1(8);         stage B1(kt+1);          bar; lgkm0; 16 MFMA; vmcnt4; bar
//  ph3:                       stage A1(kt+1);          bar; lgkm0; 16 MFMA; vmcnt4; bar
// Ledger: half-tile staged at phase p is vmcnt(4)-confirmed at p+2, read at p+3/p+4 (RAW ok);
// its dbuf slot was last ds_read 4 phases before the stage issues (WAR ok). Never drains.
__global__ __launch_bounds__(512, 2)
void gemm_qkv(const unsigned short* __restrict__ A, const unsigned short* __restrict__ Bw,
              unsigned short* __restrict__ Qg, unsigned short* __restrict__ Kg,
              unsigned short* __restrict__ Vt,
              const float* __restrict__ alphap, const float* __restrict__ halfp) {
  const int K = 1024, NT = 16;
  __shared__ __align__(16) unsigned short lds[65536];  // elems: A [0,32768), B [32768,65536)
  const int tid = threadIdx.x, lane = tid & 63, wv = tid >> 6;
  const int wm = wv >> 2, wn = wv & 3;
  const int lg = lane >> 4, lr = lane & 15;
  // XCD swizzle: 48 blocks/XCD, bx-outer -> per-XCD 4 A-stripes + 12 B-panels (59MB verified)
  const int s = (blockIdx.x & 7) * 48 + (blockIdx.x >> 3);
  const int bx = s / 12, by = s % 12;

  // staging: half-tile = 128x64 bf16 = 1024 chunks of 16B; thread owns chunks tid, tid+512
  const int c0 = tid, c1 = tid + 512;
  const int r0 = c0 >> 3, g0 = (c0 & 7) ^ (r0 & 7);
  const int r1 = c1 >> 3, g1 = (c1 & 7) ^ (r1 & 7);
  const unsigned short* AgH[2][2];
  const unsigned short* BgH[2][2];
#pragma unroll
  for (int hf = 0; hf < 2; ++hf) {
    AgH[hf][0] = A + (size_t)(bx * 256 + hf * 128 + r0) * K + g0 * 8;
    AgH[hf][1] = A + (size_t)(bx * 256 + hf * 128 + r1) * K + g1 * 8;
    BgH[hf][0] = Bw + (size_t)(by * 256 + hf * 128 + r0) * K + g0 * 8;
    BgH[hf][1] = Bw + (size_t)(by * 256 + hf * 128 + r1) * K + g1 * 8;
  }
  const int o0 = c0 * 16, o1 = c1 * 16;  // byte offsets within a half-slot

#define STG_A(hf, kt)                                                          \
  do {                                                                         \
    char* base = (char*)lds + ((kt) & 1) * 32768 + (hf) * 16384;               \
    gload16(AgH[hf][0] + (size_t)(kt) * 64, base + o0);                        \
    gload16(AgH[hf][1] + (size_t)(kt) * 64, base + o1);                        \
  } while (0)
#define STG_B(hf, kt)                                                          \
  do {                                                                         \
    char* base = (char*)lds + 65536 + ((kt) & 1) * 32768 + (hf) * 16384;       \
    gload16(BgH[hf][0] + (size_t)(kt) * 64, base + o0);                        \
    gload16(BgH[hf][1] + (size_t)(kt) * 64, base + o1);                        \
  } while (0)
#define PH_ENTRY                                                               \
  __builtin_amdgcn_s_barrier();                                                \
  asm volatile("s_waitcnt lgkmcnt(0)" ::: "memory")
#define PH_EXIT                                                                \
  asm volatile("s_waitcnt vmcnt(4)" ::: "memory");                             \
  __builtin_amdgcn_s_barrier();                                                \
  asm volatile("" ::: "memory")

  f32x4 acc00[4][2] = {}, acc01[4][2] = {}, acc10[4][2] = {}, acc11[4][2] = {};
  const int pos0 = lg ^ (lr & 7), pos1 = (4 + lg) ^ (lr & 7);

  // prologue: stage kt0 fully; one-time drain
  STG_A(0, 0); STG_B(0, 0); STG_B(1, 0); STG_A(1, 0);
  asm volatile("s_waitcnt vmcnt(0)" ::: "memory");
  __builtin_amdgcn_s_barrier();
  asm volatile("" ::: "memory");

  for (int kt = 0; kt < NT; ++kt) {
    const int par = kt & 1;
    const unsigned short* Ap = lds + par * 16384;
    const unsigned short* Bp = lds + 32768 + par * 16384;
    bf16x8 a[4][2], b0[2][2], b1[2][2];

    // ---- phase 0: read A-h0(8) + B-h0(4); stage A0(kt+1); MFMA q(0,0)
#pragma unroll
    for (int mf = 0; mf < 4; ++mf) {
      const int ro = (wm * 64 + mf * 16 + lr) * 64;
      a[mf][0] = *(const bf16x8*)(Ap + ro + pos0 * 8);
      a[mf][1] = *(const bf16x8*)(Ap + ro + pos1 * 8);
    }
#pragma unroll
    for (int nf = 0; nf < 2; ++nf) {
      const int ro = (wn * 32 + nf * 16 + lr) * 64;
      b0[nf][0] = *(const bf16x8*)(Bp + ro + pos0 * 8);
      b0[nf][1] = *(const bf16x8*)(Bp + ro + pos1 * 8);
    }
    if (kt + 1 < NT) STG_A(0, kt + 1);
    asm volatile("s_waitcnt lgkmcnt(8)" ::: "memory");
    PH_ENTRY;
    __builtin_amdgcn_s_setprio(1);
#pragma unroll
    for (int mf = 0; mf < 4; ++mf)
#pragma unroll
      for (int nf = 0; nf < 2; ++nf)
#pragma unroll
        for (int kk = 0; kk < 2; ++kk)
          acc00[mf][nf] = mfma16(a[mf][kk], b0[nf][kk], acc00[mf][nf]);
    __builtin_amdgcn_s_setprio(0);
    PH_EXIT;

    // ---- phase 1: read B-h1(4); stage B0(kt+1); MFMA q(0,1)
#pragma unroll
    for (int nf = 0; nf < 2; ++nf) {
      const int ro = (wn * 32 + nf * 16 + lr) * 64;
      b1[nf][0] = *(const bf16x8*)(Bp + 8192 + ro + pos0 * 8);
      b1[nf][1] = *(const bf16x8*)(Bp + 8192 + ro + pos1 * 8);
    }
    if (kt + 1 < NT) STG_B(0, kt + 1);
    PH_ENTRY;
    __builtin_amdgcn_s_setprio(1);
#pragma unroll
    for (int mf = 0; mf < 4; ++mf)
#pragma unroll
      for (int nf = 0; nf < 2; ++nf)
#pragma unroll
        for (int kk = 0; kk < 2; ++kk)
          acc01[mf][nf] = mfma16(a[mf][kk], b1[nf][kk], acc01[mf][nf]);
    __builtin_amdgcn_s_setprio(0);
    PH_EXIT;

    // ---- phase 2: read A-h1(8); stage B1(kt+1); MFMA q(1,0)
#pragma unroll
    for (int mf = 0; mf < 4; ++mf) {
      const int ro = (wm * 64 + mf * 16 + lr) * 64;
      a[mf][0] = *(const bf16x8*)(Ap + 8192 + ro + pos0 * 8);
      a[mf][1] = *(const bf16x8*)(Ap + 8192 + ro + pos1 * 8);
    }
    if (kt + 1 < NT) STG_B(1, kt + 1);
    PH_ENTRY;
    __builtin_amdgcn_s_setprio(1);
#pragma unroll
    for (int mf = 0; mf < 4; ++mf)
#pragma unroll
      for (int nf = 0; nf < 2; ++nf)
#pragma unroll
        for (int kk = 0; kk < 2; ++kk)
          acc10[mf][nf] = mfma16(a[mf][kk], b0[nf][kk], acc10[mf][nf]);
    __builtin_amdgcn_s_setprio(0);
    PH_EXIT;

    // ---- phase 3: stage A1(kt+1); MFMA q(1,1)
    if (kt + 1 < NT) STG_A(1, kt + 1);
    PH_ENTRY;
    __builtin_amdgcn_s_setprio(1);
#pragma unroll
    for (int mf = 0; mf < 4; ++mf)
#pragma unroll
      for (int nf = 0; nf < 2; ++nf)
#pragma unroll
        for (int kk = 0; kk < 2; ++kk)
          acc11[mf][nf] = mfma16(a[mf][kk], b1[nf][kk], acc11[mf][nf]);
    __builtin_amdgcn_s_setprio(0);
    PH_EXIT;
  }
#undef STG_A
#undef STG_B
#undef PH_ENTRY
#undef PH_EXIT

  // epilogue: scatter to Q / K(+64) / V^T(+64)
  const int slot = by >> 2;            // 0=q 1=k 2=v (256-col tiles never straddle)
  const int csIn = (by & 3) * 256;
  const float sc = (slot == 0) ? 0.18033688011112042f : (alphap[0] * halfp[0]);
#pragma unroll
  for (int qm = 0; qm < 2; ++qm)
#pragma unroll
    for (int qn = 0; qn < 2; ++qn)
#pragma unroll
      for (int mf = 0; mf < 4; ++mf) {
        const int grow0 = bx * 256 + qm * 128 + wm * 64 + mf * 16 + lg * 4;
#pragma unroll
        for (int nf = 0; nf < 2; ++nf) {
          const int gcol = csIn + qn * 128 + wn * 32 + nf * 16 + lr;
          const int h = gcol >> 6, d = gcol & 63;
#pragma unroll
          for (int j = 0; j < 4; ++j) {
            const int grow = grow0 + j;
            const int b = grow >> 10, nn = grow & 1023;
            const f32x4* accp = qm == 0 ? (qn == 0 ? &acc00[mf][nf] : &acc01[mf][nf])
                                        : (qn == 0 ? &acc10[mf][nf] : &acc11[mf][nf]);
            const unsigned short u = f2bf((*accp)[j] * sc);
            if (slot == 0)      Qg[(((size_t)b * NH + h) * NSEQ + nn) * NHD + d] = u;
            else if (slot == 1) Kg[(((size_t)b * NH + h) * NKV + NP + nn) * NHD + d] = u;
            else                Vt[(((size_t)b * NH + h) * NHD + d) * NKV + NP + nn] = u;
          }
        }
      }
}

// ---------------- proj GEMM (r3-proven 128x128, BK=64 dbuf, counted vmcnt) ----------------
__global__ __launch_bounds__(256, 2)
void gemm_proj(const unsigned short* __restrict__ A, const unsigned short* __restrict__ Bw,
               float* __restrict__ Cout, const float* __restrict__ bias) {
  const int K = 1024;
  __shared__ __align__(16) unsigned short ldsA[2][128 * 64];
  __shared__ __align__(16) unsigned short ldsB[2][128 * 64];
  const int tid = threadIdx.x, lane = tid & 63, wv = tid >> 6;
  const int wr = wv >> 1, wc = wv & 1;
  const int lg = lane >> 4, lr = lane & 15;
  const int bx = blockIdx.x, by = blockIdx.y;

  f32x4 acc[4][4] = {};

  const unsigned short* Ag[4];
  const unsigned short* Bg[4];
  int ldof[4];
#pragma unroll
  for (int i = 0; i < 4; ++i) {
    const int c = tid + 256 * i;
    const int row = c >> 3;
    const int gch = (c & 7) ^ (row & 7);
    Ag[i] = A + (size_t)(bx * 128 + row) * K + gch * 8;
    Bg[i] = Bw + (size_t)(by * 128 + row) * K + gch * 8;
    ldof[i] = c * 16;
  }

#define GSTAGE(t, bsel)                                                        \
  do {                                                                         \
    char* lA = (char*)&ldsA[bsel][0];                                          \
    char* lB = (char*)&ldsB[bsel][0];                                          \
    _Pragma("unroll") for (int i = 0; i < 4; ++i)                              \
        gload16(Ag[i] + (size_t)(t) * 64, lA + ldof[i]);                       \
    _Pragma("unroll") for (int i = 0; i < 4; ++i)                              \
        gload16(Bg[i] + (size_t)(t) * 64, lB + ldof[i]);                       \
  } while (0)

  const int nst = K >> 6;  // 16
  int buf = 0;
  GSTAGE(0, 0);
  for (int t = 0; t < nst; ++t) {
    if (t < nst - 1) {
      GSTAGE(t + 1, buf ^ 1);
      asm volatile("s_waitcnt vmcnt(8)" ::: "memory");
    } else {
      asm volatile("s_waitcnt vmcnt(0)" ::: "memory");
    }
    __builtin_amdgcn_s_barrier();
    asm volatile("" ::: "memory");

#pragma unroll
    for (int kk = 0; kk < 2; ++kk) {
      bf16x8 af[4], bfm[4];
#pragma unroll
      for (int m = 0; m < 4; ++m) {
        const int row = wr * 64 + m * 16 + lr;
        const int pos = (kk * 4 + lg) ^ (row & 7);
        af[m] = *(const bf16x8*)(&ldsA[buf][0] + row * 64 + pos * 8);
      }
#pragma unroll
      for (int n = 0; n < 4; ++n) {
        const int row = wc * 64 + n * 16 + lr;
        const int pos = (kk * 4 + lg) ^ (row & 7);
        bfm[n] = *(const bf16x8*)(&ldsB[buf][0] + row * 64 + pos * 8);
      }
      __builtin_amdgcn_s_setprio(1);
#pragma unroll
      for (int m = 0; m < 4; ++m)
#pragma unroll
        for (int n = 0; n < 4; ++n)
          acc[m][n] = mfma16(af[m], bfm[n], acc[m][n]);
      __builtin_amdgcn_s_setprio(0);
    }

    asm volatile("s_waitcnt lgkmcnt(0)" ::: "memory");
    __builtin_amdgcn_s_barrier();
    asm volatile("" ::: "memory");
    buf ^= 1;
  }
#undef GSTAGE

#pragma unroll
  for (int m = 0; m < 4; ++m) {
    const int grow0 = bx * 128 + wr * 64 + m * 16 + lg * 4;
#pragma unroll
    for (int n = 0; n < 4; ++n) {
      const int gcol = by * 128 + wc * 64 + n * 16 + lr;
      const float bb = bias[gcol];
#pragma unroll
      for (int j = 0; j < 4; ++j)
        Cout[(size_t)(grow0 + j) * NC + gcol] = acc[m][n][j] + bb;
    }
  }
}

// ---------------- flash attention (r3-proven: QBLK=128, 4 waves, swapped QK^T) ----------------
__global__ __launch_bounds__(256, 3)
void attn_fwd(const unsigned short* __restrict__ Qg, const unsigned short* __restrict__ Kg,
              const unsigned short* __restrict__ Vt, unsigned short* __restrict__ Oat) {
  __shared__ __align__(16) unsigned short Klds[2][64 * 64];
  __shared__ __align__(16) unsigned short Vlds[2][64 * 64];
  __shared__ __align__(16) unsigned short Plds[4 * 32 * 64];
  const int tid = threadIdx.x, lane = tid & 63, wv = tid >> 6;
  const int bh = blockIdx.x & 127;
  const int q0 = (blockIdx.x >> 7) * 128;
  const int lg = lane >> 4, lr = lane & 15;

  bf16x8 bq[2][2];
#pragma unroll
  for (int nq = 0; nq < 2; ++nq)
#pragma unroll
    for (int kk = 0; kk < 2; ++kk)
      bq[nq][kk] = *(const bf16x8*)(Qg + ((size_t)bh * NSEQ + q0 + wv * 32 + nq * 16 + lr) * NHD + kk * 32 + lg * 8);

  f32x4 oac[2][4] = {};
  float mrun[2] = {-1e30f, -1e30f};
  float lrun[2] = {0.f, 0.f};

  const int kr0 = tid >> 3, kc = tid & 7;
  const int sw = kc ^ (kr0 & 7);
  const unsigned short* Kgp = Kg + ((size_t)bh * NKV + kr0) * NHD + sw * 8;
  const unsigned short* Vgp = Vt + ((size_t)bh * NHD + kr0) * NKV + sw * 8;
  unsigned short* Pw = Plds + wv * 2048;

#define STAGE(t, bsel)                                                      \
  do {                                                                      \
    unsigned short* kb = &Klds[bsel][0] + wv * 512;                         \
    unsigned short* vb = &Vlds[bsel][0] + wv * 512;                         \
    gload16(Kgp + (size_t)(t) * 4096, kb);                                  \
    gload16(Kgp + (size_t)(t) * 4096 + 32 * NHD, kb + 2048);                \
    gload16(Vgp + (size_t)(t) * 64, vb);                                    \
    gload16(Vgp + (size_t)(t) * 64 + (size_t)32 * NKV, vb + 2048);          \
  } while (0)

  STAGE(0, 0);
  asm volatile("s_waitcnt vmcnt(0)" ::: "memory");
  __builtin_amdgcn_s_barrier();

  for (int t = 0; t < 17; ++t) {
    const int b = t & 1;
    if (t < 16) STAGE(t + 1, b ^ 1);

    f32x4 sa[4][2] = {};
    __builtin_amdgcn_s_setprio(1);
#pragma unroll
    for (int kk = 0; kk < 2; ++kk) {
      bf16x8 ak[4];
#pragma unroll
      for (int mk = 0; mk < 4; ++mk) {
        const int row = mk * 16 + lr;
        const int cc = (kk * 4 + lg) ^ (row & 7);
        ak[mk] = *(const bf16x8*)(&Klds[b][0] + row * 64 + cc * 8);
      }
#pragma unroll
      for (int mk = 0; mk < 4; ++mk)
#pragma unroll
        for (int nq = 0; nq < 2; ++nq)
          sa[mk][nq] = mfma16(ak[mk], bq[nq][kk], sa[mk][nq]);
    }
    __builtin_amdgcn_s_setprio(0);

    float tmx[2];
#pragma unroll
    for (int nq = 0; nq < 2; ++nq) {
      f32x4 m4 = sa[0][nq];
#pragma unroll
      for (int mk = 1; mk < 4; ++mk)
#pragma unroll
        for (int j = 0; j < 4; ++j) m4[j] = fmaxf(m4[j], sa[mk][nq][j]);
      float tm = fmaxf(fmaxf(m4[0], m4[1]), fmaxf(m4[2], m4[3]));
      tm = fmaxf(tm, __shfl_xor(tm, 16));
      tm = fmaxf(tm, __shfl_xor(tm, 32));
      tmx[nq] = tm;
    }
    const bool upd = !__all((tmx[0] <= mrun[0] + 8.f) && (tmx[1] <= mrun[1] + 8.f));
    if (upd) {
      const float nm0 = fmaxf(mrun[0], tmx[0]);
      const float nm1 = fmaxf(mrun[1], tmx[1]);
      const float e0 = __builtin_amdgcn_exp2f(mrun[0] - nm0);
      const float e1 = __builtin_amdgcn_exp2f(mrun[1] - nm1);
      mrun[0] = nm0; mrun[1] = nm1;
      lrun[0] *= e0; lrun[1] *= e1;
#pragma unroll
      for (int m = 0; m < 2; ++m)
#pragma unroll
        for (int j = 0; j < 4; ++j) {
          const float fe = __shfl(m ? e1 : e0, lg * 4 + j, 16);
#pragma unroll
          for (int df = 0; df < 4; ++df) oac[m][df][j] *= fe;
        }
    }
#pragma unroll
    for (int nq = 0; nq < 2; ++nq) {
#pragma unroll
      for (int mk = 0; mk < 4; ++mk)
#pragma unroll
        for (int j = 0; j < 4; ++j)
          sa[mk][nq][j] = __builtin_amdgcn_exp2f(sa[mk][nq][j] - mrun[nq]);
      f32x4 s4 = sa[0][nq];
#pragma unroll
      for (int mk = 1; mk < 4; ++mk)
#pragma unroll
        for (int j = 0; j < 4; ++j) s4[j] += sa[mk][nq][j];
      float s = (s4[0] + s4[1]) + (s4[2] + s4[3]);
      s += __shfl_xor(s, 16);
      s += __shfl_xor(s, 32);
      lrun[nq] += s;
      const int q = nq * 16 + lr;
#pragma unroll
      for (int mk = 0; mk < 4; ++mk) {
        const int c = mk * 2 + (lg >> 1);
        uint2 uu;
        uu.x = (unsigned)f2bf(sa[mk][nq][0]) | ((unsigned)f2bf(sa[mk][nq][1]) << 16);
        uu.y = (unsigned)f2bf(sa[mk][nq][2]) | ((unsigned)f2bf(sa[mk][nq][3]) << 16);
        *(uint2*)(Pw + q * 64 + ((c ^ (q & 7)) << 3) + (lg & 1) * 4) = uu;
      }
    }

    __builtin_amdgcn_s_setprio(1);
#pragma unroll
    for (int kk = 0; kk < 2; ++kk) {
      bf16x8 bv[4], ap[2];
#pragma unroll
      for (int df = 0; df < 4; ++df) {
        const int d = df * 16 + lr;
        const int cc = (kk * 4 + lg) ^ (d & 7);
        bv[df] = *(const bf16x8*)(&Vlds[b][0] + d * 64 + cc * 8);
      }
#pragma unroll
      for (int m = 0; m < 2; ++m) {
        const int q = m * 16 + lr;
        const int pos = (kk * 4 + lg) ^ (q & 7);
        ap[m] = *(const bf16x8*)(Pw + q * 64 + pos * 8);
      }
#pragma unroll
      for (int m = 0; m < 2; ++m)
#pragma unroll
        for (int df = 0; df < 4; ++df)
          oac[m][df] = mfma16(ap[m], bv[df], oac[m][df]);
    }
    __builtin_amdgcn_s_setprio(0);

    asm volatile("s_waitcnt vmcnt(0)" ::: "memory");
    __builtin_amdgcn_s_barrier();
  }
#undef STAGE

  const int bidx = bh >> 4, h = bh & 15;
  const float l0 = 1.f / lrun[0], l1 = 1.f / lrun[1];
#pragma unroll
  for (int m = 0; m < 2; ++m) {
#pragma unroll
    for (int j = 0; j < 4; ++j) {
      const float fi = __shfl(m ? l1 : l0, lg * 4 + j, 16);
      const int row = q0 + wv * 32 + m * 16 + lg * 4 + j;
#pragma unroll
      for (int df = 0; df < 4; ++df) {
        const int col = h * 64 + df * 16 + lr;
        Oat[((size_t)bidx * NSEQ + row) * NC + col] = f2bf(oac[m][df][j] * fi);
      }
    }
  }
}

// ---------------- launch ----------------
extern "C" void kernel_launch(void* const* d_in, const int* in_sizes, int n_in,
                              void* d_out, int out_size, void* d_ws, size_t ws_size,
                              hipStream_t stream) {
  const float* x      = (const float*)d_in[0];
  const float* prompt = (const float*)d_in[1];
  const float* alpha  = (const float*)d_in[2];
  const float* halfa  = (const float*)d_in[3];
  const float* Wqkv   = (const float*)d_in[4];
  const float* Wproj  = (const float*)d_in[5];
  const float* bproj  = (const float*)d_in[6];
  float* out = (float*)d_out;

  unsigned short* ws    = (unsigned short*)d_ws;
  unsigned short* x_bf  = ws;
  unsigned short* w_bf  = x_bf + (size_t)8192 * 1024;
  unsigned short* wp_bf = w_bf + (size_t)3072 * 1024;
  unsigned short* Qg    = wp_bf + (size_t)1024 * 1024;
  unsigned short* Kg    = Qg + (size_t)NB * NH * NSEQ * NHD;
  unsigned short* Vt    = Kg + (size_t)NB * NH * NKV * NHD;
  unsigned short* Oat   = Vt + (size_t)NB * NH * NKV * NHD;

  pack_all<<<12288, 256, 0, stream>>>(x, Wqkv, Wproj, x_bf, w_bf, wp_bf);
  prefix_pack<<<512, 256, 0, stream>>>(prompt, Kg, Vt, alpha);

  // QKV: M=8192 N=3072 -> 32 x 12 = 384 blocks of 256^2
  gemm_qkv<<<384, 512, 0, stream>>>(x_bf, w_bf, Qg, Kg, Vt, alpha, halfa);
  attn_fwd<<<1024, 256, 0, stream>>>(Qg, Kg, Vt, Oat);
  // proj: M=8192 N=1024 -> 64 x 8 of 128^2
  gemm_proj<<<dim3(64, 8), 256, 0, stream>>>(Oat, wp_bf, out, bproj);
}

// Round 9
// 187.505 us; speedup vs baseline: 1.0651x; 1.0604x over previous
//
#include <hip/hip_runtime.h>

typedef float f32x4 __attribute__((ext_vector_type(4)));
typedef short bf16x8 __attribute__((ext_vector_type(8)));

#define NB 8
#define NH 16
#define NSEQ 1024
#define NP 64
#define NKV 1088
#define NC 1024
#define NHD 64

__device__ __forceinline__ unsigned short f2bf(float f) {
  unsigned int u = __builtin_bit_cast(unsigned int, f);
  u += 0x7fffu + ((u >> 16) & 1u);  // RNE
  return (unsigned short)(u >> 16);
}

__device__ __forceinline__ void gload16(const void* g, void* l) {
  __builtin_amdgcn_global_load_lds((const __attribute__((address_space(1))) void*)g,
                                   (__attribute__((address_space(3))) void*)l, 16, 0, 0);
}

__device__ __forceinline__ f32x4 mfma16(bf16x8 a, bf16x8 b, f32x4 c) {
  return __builtin_amdgcn_mfma_f32_16x16x32_bf16(a, b, c, 0, 0, 0);
}

// ---------------- fused pack kernel ----------------
// blocks [0,12288): f32->bf16 for x / Wqkv / Wproj (3145728 float4s)
// blocks [12288,12800): prompt -> Kg prefix (*a) + Vt prefix (*a, transposed)
__global__ void pack_fused(const float* __restrict__ x, const float* __restrict__ wq,
                           const float* __restrict__ wp, const float* __restrict__ prompt,
                           unsigned short* __restrict__ xd, unsigned short* __restrict__ wqd,
                           unsigned short* __restrict__ wpd, unsigned short* __restrict__ Kg,
                           unsigned short* __restrict__ Vt, const float* __restrict__ alpha) {
  if (blockIdx.x < 12288) {
    int i = blockIdx.x * 256 + threadIdx.x;
    const float* s;
    unsigned short* d;
    int off;
    if (i < 2097152) { s = x; d = xd; off = i; }
    else if (i < 2883584) { s = wq; d = wqd; off = i - 2097152; }
    else { s = wp; d = wpd; off = i - 2883584; }
    float4 v = ((const float4*)s)[off];
    ushort4 o;
    o.x = f2bf(v.x); o.y = f2bf(v.y); o.z = f2bf(v.z); o.w = f2bf(v.w);
    ((ushort4*)d)[off] = o;
  } else {
    int i = (blockIdx.x - 12288) * 256 + threadIdx.x;  // 131072 total
    float a = alpha[0];
    int d4 = i & 15, p = (i >> 4) & 63, h = (i >> 10) & 15, b = i >> 14;
    const float4 kv = *(const float4*)(prompt + ((((size_t)(b * 2 + 0) * NP + p) * NH + h) * NHD + d4 * 4));
    ushort4 ko;
    ko.x = f2bf(kv.x * a); ko.y = f2bf(kv.y * a); ko.z = f2bf(kv.z * a); ko.w = f2bf(kv.w * a);
    *(ushort4*)(Kg + (((size_t)(b * NH + h) * NKV + p) * NHD + d4 * 4)) = ko;
    const float4 vv = *(const float4*)(prompt + ((((size_t)(b * 2 + 1) * NP + p) * NH + h) * NHD + d4 * 4));
    size_t vbase = ((size_t)(b * NH + h) * NHD + d4 * 4) * NKV + p;
    Vt[vbase]            = f2bf(vv.x * a);
    Vt[vbase + NKV]      = f2bf(vv.y * a);
    Vt[vbase + 2 * NKV]  = f2bf(vv.z * a);
    Vt[vbase + 3 * NKV]  = f2bf(vv.w * a);
  }
}

// ---------------- GEMM (B^T layout: out[m,c] = sum_k A[m,k]*Bw[c,k]) ----------------
// r3-proven: 128x128 tile, BK=64, double-buffered LDS, counted-vmcnt 2-phase pipeline.
template <int MODE>
__global__ __launch_bounds__(256, 2)
void gemm_bt(const unsigned short* __restrict__ A, const unsigned short* __restrict__ Bw, int K,
             unsigned short* __restrict__ Qg, unsigned short* __restrict__ Kg,
             unsigned short* __restrict__ Vt,
             const float* __restrict__ alphap, const float* __restrict__ halfp,
             float* __restrict__ Cout, const float* __restrict__ bias) {
  __shared__ __align__(16) unsigned short ldsA[2][128 * 64];
  __shared__ __align__(16) unsigned short ldsB[2][128 * 64];
  const int tid = threadIdx.x, lane = tid & 63, wv = tid >> 6;
  const int wr = wv >> 1, wc = wv & 1;
  const int lg = lane >> 4, lr = lane & 15;
  const int bx = blockIdx.x, by = blockIdx.y;

  f32x4 acc[4][4] = {};

  const unsigned short* Ag[4];
  const unsigned short* Bg[4];
  int ldof[4];
#pragma unroll
  for (int i = 0; i < 4; ++i) {
    const int c = tid + 256 * i;
    const int row = c >> 3;
    const int gch = (c & 7) ^ (row & 7);
    Ag[i] = A + (size_t)(bx * 128 + row) * K + gch * 8;
    Bg[i] = Bw + (size_t)(by * 128 + row) * K + gch * 8;
    ldof[i] = c * 16;
  }

#define GSTAGE(t, bsel)                                                        \
  do {                                                                         \
    char* lA = (char*)&ldsA[bsel][0];                                          \
    char* lB = (char*)&ldsB[bsel][0];                                          \
    _Pragma("unroll") for (int i = 0; i < 4; ++i)                              \
        gload16(Ag[i] + (size_t)(t) * 64, lA + ldof[i]);                       \
    _Pragma("unroll") for (int i = 0; i < 4; ++i)                              \
        gload16(Bg[i] + (size_t)(t) * 64, lB + ldof[i]);                       \
  } while (0)

  const int nst = K >> 6;  // 16
  int buf = 0;
  GSTAGE(0, 0);
  for (int t = 0; t < nst; ++t) {
    if (t < nst - 1) {
      GSTAGE(t + 1, buf ^ 1);
      asm volatile("s_waitcnt vmcnt(8)" ::: "memory");  // t landed; t+1 in flight
    } else {
      asm volatile("s_waitcnt vmcnt(0)" ::: "memory");
    }
    __builtin_amdgcn_s_barrier();
    asm volatile("" ::: "memory");

#pragma unroll
    for (int kk = 0; kk < 2; ++kk) {
      bf16x8 af[4], bfm[4];
#pragma unroll
      for (int m = 0; m < 4; ++m) {
        const int row = wr * 64 + m * 16 + lr;
        const int pos = (kk * 4 + lg) ^ (row & 7);
        af[m] = *(const bf16x8*)(&ldsA[buf][0] + row * 64 + pos * 8);
      }
#pragma unroll
      for (int n = 0; n < 4; ++n) {
        const int row = wc * 64 + n * 16 + lr;
        const int pos = (kk * 4 + lg) ^ (row & 7);
        bfm[n] = *(const bf16x8*)(&ldsB[buf][0] + row * 64 + pos * 8);
      }
      __builtin_amdgcn_s_setprio(1);
#pragma unroll
      for (int m = 0; m < 4; ++m)
#pragma unroll
        for (int n = 0; n < 4; ++n)
          acc[m][n] = mfma16(af[m], bfm[n], acc[m][n]);
      __builtin_amdgcn_s_setprio(0);
    }

    asm volatile("s_waitcnt lgkmcnt(0)" ::: "memory");
    __builtin_amdgcn_s_barrier();
    asm volatile("" ::: "memory");
    buf ^= 1;
  }
#undef GSTAGE

  if constexpr (MODE == 0) {
    const int slot = (by * 128) >> 10;
    const int csIn = (by * 128) & 1023;
    // Q gets softmax scale folded in base-2 domain: 0.125 * log2(e)
    const float sc = (slot == 0) ? 0.18033688011112042f : (alphap[0] * halfp[0]);
#pragma unroll
    for (int m = 0; m < 4; ++m) {
      const int grow0 = bx * 128 + wr * 64 + m * 16 + lg * 4;
#pragma unroll
      for (int n = 0; n < 4; ++n) {
        const int gcol = csIn + wc * 64 + n * 16 + lr;
        const int h = gcol >> 6, d = gcol & 63;
#pragma unroll
        for (int j = 0; j < 4; ++j) {
          const int grow = grow0 + j;
          const int b = grow >> 10, nn = grow & 1023;
          const unsigned short u = f2bf(acc[m][n][j] * sc);
          if (slot == 0)      Qg[(((size_t)b * NH + h) * NSEQ + nn) * NHD + d] = u;
          else if (slot == 1) Kg[(((size_t)b * NH + h) * NKV + NP + nn) * NHD + d] = u;
          else                Vt[(((size_t)b * NH + h) * NHD + d) * NKV + NP + nn] = u;
        }
      }
    }
  } else {
#pragma unroll
    for (int m = 0; m < 4; ++m) {
      const int grow0 = bx * 128 + wr * 64 + m * 16 + lg * 4;
#pragma unroll
      for (int n = 0; n < 4; ++n) {
        const int gcol = by * 128 + wc * 64 + n * 16 + lr;
        const float bb = bias[gcol];
#pragma unroll
        for (int j = 0; j < 4; ++j)
          Cout[(size_t)(grow0 + j) * NC + gcol] = acc[m][n][j] + bb;
      }
    }
  }
}

// ---------------- flash attention (r3-proven: QBLK=128, 4 waves, swapped QK^T) ----------------
__global__ __launch_bounds__(256, 3)
void attn_fwd(const unsigned short* __restrict__ Qg, const unsigned short* __restrict__ Kg,
              const unsigned short* __restrict__ Vt, unsigned short* __restrict__ Oat) {
  __shared__ __align__(16) unsigned short Klds[2][64 * 64];
  __shared__ __align__(16) unsigned short Vlds[2][64 * 64];
  __shared__ __align__(16) unsigned short Plds[4 * 32 * 64];
  const int tid = threadIdx.x, lane = tid & 63, wv = tid >> 6;
  const int bh = blockIdx.x & 127;
  const int q0 = (blockIdx.x >> 7) * 128;
  const int lg = lane >> 4, lr = lane & 15;

  bf16x8 bq[2][2];
#pragma unroll
  for (int nq = 0; nq < 2; ++nq)
#pragma unroll
    for (int kk = 0; kk < 2; ++kk)
      bq[nq][kk] = *(const bf16x8*)(Qg + ((size_t)bh * NSEQ + q0 + wv * 32 + nq * 16 + lr) * NHD + kk * 32 + lg * 8);

  f32x4 oac[2][4] = {};
  float mrun[2] = {-1e30f, -1e30f};
  float lrun[2] = {0.f, 0.f};

  const int kr0 = tid >> 3, kc = tid & 7;
  const int sw = kc ^ (kr0 & 7);
  const unsigned short* Kgp = Kg + ((size_t)bh * NKV + kr0) * NHD + sw * 8;
  const unsigned short* Vgp = Vt + ((size_t)bh * NHD + kr0) * NKV + sw * 8;
  unsigned short* Pw = Plds + wv * 2048;

#define STAGE(t, bsel)                                                      \
  do {                                                                      \
    unsigned short* kb = &Klds[bsel][0] + wv * 512;                         \
    unsigned short* vb = &Vlds[bsel][0] + wv * 512;                         \
    gload16(Kgp + (size_t)(t) * 4096, kb);                                  \
    gload16(Kgp + (size_t)(t) * 4096 + 32 * NHD, kb + 2048);                \
    gload16(Vgp + (size_t)(t) * 64, vb);                                    \
    gload16(Vgp + (size_t)(t) * 64 + (size_t)32 * NKV, vb + 2048);          \
  } while (0)

  STAGE(0, 0);
  asm volatile("s_waitcnt vmcnt(0)" ::: "memory");
  __builtin_amdgcn_s_barrier();

  for (int t = 0; t < 17; ++t) {
    const int b = t & 1;
    if (t < 16) STAGE(t + 1, b ^ 1);

    f32x4 sa[4][2] = {};
    __builtin_amdgcn_s_setprio(1);
#pragma unroll
    for (int kk = 0; kk < 2; ++kk) {
      bf16x8 ak[4];
#pragma unroll
      for (int mk = 0; mk < 4; ++mk) {
        const int row = mk * 16 + lr;
        const int cc = (kk * 4 + lg) ^ (row & 7);
        ak[mk] = *(const bf16x8*)(&Klds[b][0] + row * 64 + cc * 8);
      }
#pragma unroll
      for (int mk = 0; mk < 4; ++mk)
#pragma unroll
        for (int nq = 0; nq < 2; ++nq)
          sa[mk][nq] = mfma16(ak[mk], bq[nq][kk], sa[mk][nq]);
    }
    __builtin_amdgcn_s_setprio(0);

    float tmx[2];
#pragma unroll
    for (int nq = 0; nq < 2; ++nq) {
      f32x4 m4 = sa[0][nq];
#pragma unroll
      for (int mk = 1; mk < 4; ++mk)
#pragma unroll
        for (int j = 0; j < 4; ++j) m4[j] = fmaxf(m4[j], sa[mk][nq][j]);
      float tm = fmaxf(fmaxf(m4[0], m4[1]), fmaxf(m4[2], m4[3]));
      tm = fmaxf(tm, __shfl_xor(tm, 16));
      tm = fmaxf(tm, __shfl_xor(tm, 32));
      tmx[nq] = tm;
    }
    const bool upd = !__all((tmx[0] <= mrun[0] + 8.f) && (tmx[1] <= mrun[1] + 8.f));
    if (upd) {
      const float nm0 = fmaxf(mrun[0], tmx[0]);
      const float nm1 = fmaxf(mrun[1], tmx[1]);
      const float e0 = __builtin_amdgcn_exp2f(mrun[0] - nm0);
      const float e1 = __builtin_amdgcn_exp2f(mrun[1] - nm1);
      mrun[0] = nm0; mrun[1] = nm1;
      lrun[0] *= e0; lrun[1] *= e1;
#pragma unroll
      for (int m = 0; m < 2; ++m)
#pragma unroll
        for (int j = 0; j < 4; ++j) {
          const float fe = __shfl(m ? e1 : e0, lg * 4 + j, 16);
#pragma unroll
          for (int df = 0; df < 4; ++df) oac[m][df][j] *= fe;
        }
    }
#pragma unroll
    for (int nq = 0; nq < 2; ++nq) {
#pragma unroll
      for (int mk = 0; mk < 4; ++mk)
#pragma unroll
        for (int j = 0; j < 4; ++j)
          sa[mk][nq][j] = __builtin_amdgcn_exp2f(sa[mk][nq][j] - mrun[nq]);
      f32x4 s4 = sa[0][nq];
#pragma unroll
      for (int mk = 1; mk < 4; ++mk)
#pragma unroll
        for (int j = 0; j < 4; ++j) s4[j] += sa[mk][nq][j];
      float s = (s4[0] + s4[1]) + (s4[2] + s4[3]);
      s += __shfl_xor(s, 16);
      s += __shfl_xor(s, 32);
      lrun[nq] += s;
      const int q = nq * 16 + lr;
#pragma unroll
      for (int mk = 0; mk < 4; ++mk) {
        const int c = mk * 2 + (lg >> 1);
        uint2 uu;
        uu.x = (unsigned)f2bf(sa[mk][nq][0]) | ((unsigned)f2bf(sa[mk][nq][1]) << 16);
        uu.y = (unsigned)f2bf(sa[mk][nq][2]) | ((unsigned)f2bf(sa[mk][nq][3]) << 16);
        *(uint2*)(Pw + q * 64 + ((c ^ (q & 7)) << 3) + (lg & 1) * 4) = uu;
      }
    }

    __builtin_amdgcn_s_setprio(1);
#pragma unroll
    for (int kk = 0; kk < 2; ++kk) {
      bf16x8 bv[4], ap[2];
#pragma unroll
      for (int df = 0; df < 4; ++df) {
        const int d = df * 16 + lr;
        const int cc = (kk * 4 + lg) ^ (d & 7);
        bv[df] = *(const bf16x8*)(&Vlds[b][0] + d * 64 + cc * 8);
      }
#pragma unroll
      for (int m = 0; m < 2; ++m) {
        const int q = m * 16 + lr;
        const int pos = (kk * 4 + lg) ^ (q & 7);
        ap[m] = *(const bf16x8*)(Pw + q * 64 + pos * 8);
      }
#pragma unroll
      for (int m = 0; m < 2; ++m)
#pragma unroll
        for (int df = 0; df < 4; ++df)
          oac[m][df] = mfma16(ap[m], bv[df], oac[m][df]);
    }
    __builtin_amdgcn_s_setprio(0);

    asm volatile("s_waitcnt vmcnt(0)" ::: "memory");
    __builtin_amdgcn_s_barrier();
  }
#undef STAGE

  const int bidx = bh >> 4, h = bh & 15;
  const float l0 = 1.f / lrun[0], l1 = 1.f / lrun[1];
#pragma unroll
  for (int m = 0; m < 2; ++m) {
#pragma unroll
    for (int j = 0; j < 4; ++j) {
      const float fi = __shfl(m ? l1 : l0, lg * 4 + j, 16);
      const int row = q0 + wv * 32 + m * 16 + lg * 4 + j;
#pragma unroll
      for (int df = 0; df < 4; ++df) {
        const int col = h * 64 + df * 16 + lr;
        Oat[((size_t)bidx * NSEQ + row) * NC + col] = f2bf(oac[m][df][j] * fi);
      }
    }
  }
}

// ---------------- launch ----------------
extern "C" void kernel_launch(void* const* d_in, const int* in_sizes, int n_in,
                              void* d_out, int out_size, void* d_ws, size_t ws_size,
                              hipStream_t stream) {
  const float* x      = (const float*)d_in[0];
  const float* prompt = (const float*)d_in[1];
  const float* alpha  = (const float*)d_in[2];
  const float* halfa  = (const float*)d_in[3];
  const float* Wqkv   = (const float*)d_in[4];
  const float* Wproj  = (const float*)d_in[5];
  const float* bproj  = (const float*)d_in[6];
  float* out = (float*)d_out;

  unsigned short* ws    = (unsigned short*)d_ws;
  unsigned short* x_bf  = ws;
  unsigned short* w_bf  = x_bf + (size_t)8192 * 1024;
  unsigned short* wp_bf = w_bf + (size_t)3072 * 1024;
  unsigned short* Qg    = wp_bf + (size_t)1024 * 1024;
  unsigned short* Kg    = Qg + (size_t)NB * NH * NSEQ * NHD;
  unsigned short* Vt    = Kg + (size_t)NB * NH * NKV * NHD;
  unsigned short* Oat   = Vt + (size_t)NB * NH * NKV * NHD;

  pack_fused<<<12800, 256, 0, stream>>>(x, Wqkv, Wproj, prompt, x_bf, w_bf, wp_bf,
                                        Kg, Vt, alpha);

  // QKV: M=8192 N=3072 -> 64 x 24 of 128^2 (r3-proven)
  gemm_bt<0><<<dim3(64, 24), 256, 0, stream>>>(x_bf, w_bf, 1024, Qg, Kg, Vt, alpha, halfa,
                                               nullptr, nullptr);
  attn_fwd<<<1024, 256, 0, stream>>>(Qg, Kg, Vt, Oat);
  // proj: M=8192 N=1024 -> 64 x 8 of 128^2
  gemm_bt<1><<<dim3(64, 8), 256, 0, stream>>>(Oat, wp_bf, 1024, nullptr, nullptr, nullptr,
                                              nullptr, nullptr, out, bproj);
}

// Round 10
// 177.044 us; speedup vs baseline: 1.1281x; 1.0591x over previous
//
#include <hip/hip_runtime.h>

typedef float f32x4 __attribute__((ext_vector_type(4)));
typedef short bf16x8 __attribute__((ext_vector_type(8)));

#define NB 8
#define NH 16
#define NSEQ 1024
#define NP 64
#define NKV 1088
#define NC 1024
#define NHD 64

__device__ __forceinline__ unsigned short f2bf(float f) {
  unsigned int u = __builtin_bit_cast(unsigned int, f);
  u += 0x7fffu + ((u >> 16) & 1u);  // RNE
  return (unsigned short)(u >> 16);
}

__device__ __forceinline__ void gload16(const void* g, void* l) {
  __builtin_amdgcn_global_load_lds((const __attribute__((address_space(1))) void*)g,
                                   (__attribute__((address_space(3))) void*)l, 16, 0, 0);
}

__device__ __forceinline__ f32x4 mfma16(bf16x8 a, bf16x8 b, f32x4 c) {
  return __builtin_amdgcn_mfma_f32_16x16x32_bf16(a, b, c, 0, 0, 0);
}

// fragment-packed address (element granularity) for a row-major [R][1024] matrix.
// Panels of 128 rows; K-tiles of 64. Chunk order: panel, t, wr, kk, m, lane(lg*16+lr), e.
// row = panel*128 + wr*64 + m*16 + lr ; k = t*64 + kk*32 + lg*8 + e
__device__ __forceinline__ size_t fa_elem(int r, int k) {
  return (size_t)(r >> 7) * 131072 + (size_t)(k >> 6) * 8192 + ((r >> 6) & 1) * 4096 +
         ((k >> 5) & 1) * 2048 + ((r >> 4) & 3) * 512 + (((k >> 3) & 3) * 16 + (r & 15)) * 8 +
         (k & 7);
}

// ---------------- fused pack kernel ----------------
// f32 row-major -> bf16 fragment-packed for x / Wqkv / Wproj, + prompt prefix pack.
// 16B-chunk decode: lane=c&63, m=(c>>6)&3, kk=(c>>8)&1, wr=(c>>9)&1, t=(c>>10)&15, panel=c>>14.
__device__ __forceinline__ void fragpack_chunk(const float* __restrict__ src,
                                               unsigned short* __restrict__ dst, int c) {
  const int lane = c & 63, m = (c >> 6) & 3, kk = (c >> 8) & 1, wr = (c >> 9) & 1,
            t = (c >> 10) & 15, panel = c >> 14;
  const int row = panel * 128 + wr * 64 + m * 16 + (lane & 15);
  const int k = t * 64 + kk * 32 + (lane >> 4) * 8;
  const float* s = src + (size_t)row * 1024 + k;
  const float4 v0 = *(const float4*)s;
  const float4 v1 = *(const float4*)(s + 4);
  ushort4 o0, o1;
  o0.x = f2bf(v0.x); o0.y = f2bf(v0.y); o0.z = f2bf(v0.z); o0.w = f2bf(v0.w);
  o1.x = f2bf(v1.x); o1.y = f2bf(v1.y); o1.z = f2bf(v1.z); o1.w = f2bf(v1.w);
  *(ushort4*)(dst + (size_t)c * 8) = o0;
  *(ushort4*)(dst + (size_t)c * 8 + 4) = o1;
}

__global__ void pack_fused(const float* __restrict__ x, const float* __restrict__ wq,
                           const float* __restrict__ wp, const float* __restrict__ prompt,
                           unsigned short* __restrict__ xd, unsigned short* __restrict__ wqd,
                           unsigned short* __restrict__ wpd, unsigned short* __restrict__ Kg,
                           unsigned short* __restrict__ Vt, const float* __restrict__ alpha) {
  int gid = blockIdx.x * 256 + threadIdx.x;
  if (gid < 1048576) {                       // x: 8192x1024 -> 1048576 chunks
    fragpack_chunk(x, xd, gid);
  } else if (gid < 1441792) {                // Wqkv: 3072x1024 -> 393216 chunks
    fragpack_chunk(wq, wqd, gid - 1048576);
  } else if (gid < 1572864) {                // Wproj: 1024x1024 -> 131072 chunks
    fragpack_chunk(wp, wpd, gid - 1441792);
  } else {                                   // prompt prefix: 131072 threads
    int i = gid - 1572864;
    float a = alpha[0];
    int d4 = i & 15, p = (i >> 4) & 63, h = (i >> 10) & 15, b = i >> 14;
    const float4 kv = *(const float4*)(prompt + ((((size_t)(b * 2 + 0) * NP + p) * NH + h) * NHD + d4 * 4));
    ushort4 ko;
    ko.x = f2bf(kv.x * a); ko.y = f2bf(kv.y * a); ko.z = f2bf(kv.z * a); ko.w = f2bf(kv.w * a);
    *(ushort4*)(Kg + (((size_t)(b * NH + h) * NKV + p) * NHD + d4 * 4)) = ko;
    const float4 vv = *(const float4*)(prompt + ((((size_t)(b * 2 + 1) * NP + p) * NH + h) * NHD + d4 * 4));
    size_t vbase = ((size_t)(b * NH + h) * NHD + d4 * 4) * NKV + p;
    Vt[vbase]            = f2bf(vv.x * a);
    Vt[vbase + NKV]      = f2bf(vv.y * a);
    Vt[vbase + 2 * NKV]  = f2bf(vv.z * a);
    Vt[vbase + 3 * NKV]  = f2bf(vv.w * a);
  }
}

// ---------------- direct-streaming GEMM (no LDS, no barriers) ----------------
// Both operands fragment-packed; each wave loads its own fragments via coalesced
// 1KB global_load_dwordx4 (L1/L2-served), 1-deep register prefetch, full unroll.
// out[m,c] = sum_k A[m,k]*Bw[c,k]. MODE 0: QKV scatter epilogue; MODE 1: f32+bias.
template <int MODE>
__global__ __launch_bounds__(256, 2)
void gemm_direct(const unsigned short* __restrict__ Af, const unsigned short* __restrict__ Bf,
                 unsigned short* __restrict__ Qg, unsigned short* __restrict__ Kg,
                 unsigned short* __restrict__ Vt,
                 const float* __restrict__ alphap, const float* __restrict__ halfp,
                 float* __restrict__ Cout, const float* __restrict__ bias) {
  const int tid = threadIdx.x, lane = tid & 63, wv = tid >> 6;
  const int wr = wv >> 1, wc = wv & 1;
  const int lg = lane >> 4, lr = lane & 15;
  const int bx = blockIdx.x, by = blockIdx.y;

  const unsigned short* Ab = Af + (size_t)bx * 131072 + wr * 4096 + lane * 8;
  const unsigned short* Bb = Bf + (size_t)by * 131072 + wc * 4096 + lane * 8;

  f32x4 acc[4][4] = {};
  bf16x8 aC[2][4], bC[2][4], aN[2][4], bN[2][4];

#define LOADA(dst, t)                                                          \
  _Pragma("unroll") for (int kk = 0; kk < 2; ++kk)                             \
  _Pragma("unroll") for (int m = 0; m < 4; ++m)                                \
      dst[kk][m] = *(const bf16x8*)(Ab + (size_t)(t) * 8192 + kk * 2048 + m * 512)
#define LOADB(dst, t)                                                          \
  _Pragma("unroll") for (int kk = 0; kk < 2; ++kk)                             \
  _Pragma("unroll") for (int n = 0; n < 4; ++n)                                \
      dst[kk][n] = *(const bf16x8*)(Bb + (size_t)(t) * 8192 + kk * 2048 + n * 512)

  LOADA(aC, 0);
  LOADB(bC, 0);
#pragma unroll
  for (int t = 0; t < 16; ++t) {
    if (t < 15) { LOADA(aN, t + 1); LOADB(bN, t + 1); }
    __builtin_amdgcn_s_setprio(1);
#pragma unroll
    for (int kk = 0; kk < 2; ++kk)
#pragma unroll
      for (int m = 0; m < 4; ++m)
#pragma unroll
        for (int n = 0; n < 4; ++n)
          acc[m][n] = mfma16(aC[kk][m], bC[kk][n], acc[m][n]);
    __builtin_amdgcn_s_setprio(0);
#pragma unroll
    for (int kk = 0; kk < 2; ++kk)
#pragma unroll
      for (int i = 0; i < 4; ++i) { aC[kk][i] = aN[kk][i]; bC[kk][i] = bN[kk][i]; }
  }
#undef LOADA
#undef LOADB

  if constexpr (MODE == 0) {
    const int slot = (by * 128) >> 10;
    const int csIn = (by * 128) & 1023;
    // Q gets softmax scale folded in base-2 domain: 0.125 * log2(e)
    const float sc = (slot == 0) ? 0.18033688011112042f : (alphap[0] * halfp[0]);
#pragma unroll
    for (int m = 0; m < 4; ++m) {
      const int grow0 = bx * 128 + wr * 64 + m * 16 + lg * 4;
#pragma unroll
      for (int n = 0; n < 4; ++n) {
        const int gcol = csIn + wc * 64 + n * 16 + lr;
        const int h = gcol >> 6, d = gcol & 63;
#pragma unroll
        for (int j = 0; j < 4; ++j) {
          const int grow = grow0 + j;
          const int b = grow >> 10, nn = grow & 1023;
          const unsigned short u = f2bf(acc[m][n][j] * sc);
          if (slot == 0)      Qg[(((size_t)b * NH + h) * NSEQ + nn) * NHD + d] = u;
          else if (slot == 1) Kg[(((size_t)b * NH + h) * NKV + NP + nn) * NHD + d] = u;
          else                Vt[(((size_t)b * NH + h) * NHD + d) * NKV + NP + nn] = u;
        }
      }
    }
  } else {
#pragma unroll
    for (int m = 0; m < 4; ++m) {
      const int grow0 = bx * 128 + wr * 64 + m * 16 + lg * 4;
#pragma unroll
      for (int n = 0; n < 4; ++n) {
        const int gcol = by * 128 + wc * 64 + n * 16 + lr;
        const float bb = bias[gcol];
#pragma unroll
        for (int j = 0; j < 4; ++j)
          Cout[(size_t)(grow0 + j) * NC + gcol] = acc[m][n][j] + bb;
      }
    }
  }
}

// ---------------- flash attention (r3-proven; Oat written fragment-packed) ----------------
__global__ __launch_bounds__(256, 3)
void attn_fwd(const unsigned short* __restrict__ Qg, const unsigned short* __restrict__ Kg,
              const unsigned short* __restrict__ Vt, unsigned short* __restrict__ Oat) {
  __shared__ __align__(16) unsigned short Klds[2][64 * 64];
  __shared__ __align__(16) unsigned short Vlds[2][64 * 64];
  __shared__ __align__(16) unsigned short Plds[4 * 32 * 64];
  const int tid = threadIdx.x, lane = tid & 63, wv = tid >> 6;
  const int bh = blockIdx.x & 127;
  const int q0 = (blockIdx.x >> 7) * 128;
  const int lg = lane >> 4, lr = lane & 15;

  bf16x8 bq[2][2];
#pragma unroll
  for (int nq = 0; nq < 2; ++nq)
#pragma unroll
    for (int kk = 0; kk < 2; ++kk)
      bq[nq][kk] = *(const bf16x8*)(Qg + ((size_t)bh * NSEQ + q0 + wv * 32 + nq * 16 + lr) * NHD + kk * 32 + lg * 8);

  f32x4 oac[2][4] = {};
  float mrun[2] = {-1e30f, -1e30f};
  float lrun[2] = {0.f, 0.f};

  const int kr0 = tid >> 3, kc = tid & 7;
  const int sw = kc ^ (kr0 & 7);
  const unsigned short* Kgp = Kg + ((size_t)bh * NKV + kr0) * NHD + sw * 8;
  const unsigned short* Vgp = Vt + ((size_t)bh * NHD + kr0) * NKV + sw * 8;
  unsigned short* Pw = Plds + wv * 2048;

#define STAGE(t, bsel)                                                      \
  do {                                                                      \
    unsigned short* kb = &Klds[bsel][0] + wv * 512;                         \
    unsigned short* vb = &Vlds[bsel][0] + wv * 512;                         \
    gload16(Kgp + (size_t)(t) * 4096, kb);                                  \
    gload16(Kgp + (size_t)(t) * 4096 + 32 * NHD, kb + 2048);                \
    gload16(Vgp + (size_t)(t) * 64, vb);                                    \
    gload16(Vgp + (size_t)(t) * 64 + (size_t)32 * NKV, vb + 2048);          \
  } while (0)

  STAGE(0, 0);
  asm volatile("s_waitcnt vmcnt(0)" ::: "memory");
  __builtin_amdgcn_s_barrier();

  for (int t = 0; t < 17; ++t) {
    const int b = t & 1;
    if (t < 16) STAGE(t + 1, b ^ 1);

    f32x4 sa[4][2] = {};
    __builtin_amdgcn_s_setprio(1);
#pragma unroll
    for (int kk = 0; kk < 2; ++kk) {
      bf16x8 ak[4];
#pragma unroll
      for (int mk = 0; mk < 4; ++mk) {
        const int row = mk * 16 + lr;
        const int cc = (kk * 4 + lg) ^ (row & 7);
        ak[mk] = *(const bf16x8*)(&Klds[b][0] + row * 64 + cc * 8);
      }
#pragma unroll
      for (int mk = 0; mk < 4; ++mk)
#pragma unroll
        for (int nq = 0; nq < 2; ++nq)
          sa[mk][nq] = mfma16(ak[mk], bq[nq][kk], sa[mk][nq]);
    }
    __builtin_amdgcn_s_setprio(0);

    float tmx[2];
#pragma unroll
    for (int nq = 0; nq < 2; ++nq) {
      f32x4 m4 = sa[0][nq];
#pragma unroll
      for (int mk = 1; mk < 4; ++mk)
#pragma unroll
        for (int j = 0; j < 4; ++j) m4[j] = fmaxf(m4[j], sa[mk][nq][j]);
      float tm = fmaxf(fmaxf(m4[0], m4[1]), fmaxf(m4[2], m4[3]));
      tm = fmaxf(tm, __shfl_xor(tm, 16));
      tm = fmaxf(tm, __shfl_xor(tm, 32));
      tmx[nq] = tm;
    }
    const bool upd = !__all((tmx[0] <= mrun[0] + 8.f) && (tmx[1] <= mrun[1] + 8.f));
    if (upd) {
      const float nm0 = fmaxf(mrun[0], tmx[0]);
      const float nm1 = fmaxf(mrun[1], tmx[1]);
      const float e0 = __builtin_amdgcn_exp2f(mrun[0] - nm0);
      const float e1 = __builtin_amdgcn_exp2f(mrun[1] - nm1);
      mrun[0] = nm0; mrun[1] = nm1;
      lrun[0] *= e0; lrun[1] *= e1;
#pragma unroll
      for (int m = 0; m < 2; ++m)
#pragma unroll
        for (int j = 0; j < 4; ++j) {
          const float fe = __shfl(m ? e1 : e0, lg * 4 + j, 16);
#pragma unroll
          for (int df = 0; df < 4; ++df) oac[m][df][j] *= fe;
        }
    }
#pragma unroll
    for (int nq = 0; nq < 2; ++nq) {
#pragma unroll
      for (int mk = 0; mk < 4; ++mk)
#pragma unroll
        for (int j = 0; j < 4; ++j)
          sa[mk][nq][j] = __builtin_amdgcn_exp2f(sa[mk][nq][j] - mrun[nq]);
      f32x4 s4 = sa[0][nq];
#pragma unroll
      for (int mk = 1; mk < 4; ++mk)
#pragma unroll
        for (int j = 0; j < 4; ++j) s4[j] += sa[mk][nq][j];
      float s = (s4[0] + s4[1]) + (s4[2] + s4[3]);
      s += __shfl_xor(s, 16);
      s += __shfl_xor(s, 32);
      lrun[nq] += s;
      const int q = nq * 16 + lr;
#pragma unroll
      for (int mk = 0; mk < 4; ++mk) {
        const int c = mk * 2 + (lg >> 1);
        uint2 uu;
        uu.x = (unsigned)f2bf(sa[mk][nq][0]) | ((unsigned)f2bf(sa[mk][nq][1]) << 16);
        uu.y = (unsigned)f2bf(sa[mk][nq][2]) | ((unsigned)f2bf(sa[mk][nq][3]) << 16);
        *(uint2*)(Pw + q * 64 + ((c ^ (q & 7)) << 3) + (lg & 1) * 4) = uu;
      }
    }

    __builtin_amdgcn_s_setprio(1);
#pragma unroll
    for (int kk = 0; kk < 2; ++kk) {
      bf16x8 bv[4], ap[2];
#pragma unroll
      for (int df = 0; df < 4; ++df) {
        const int d = df * 16 + lr;
        const int cc = (kk * 4 + lg) ^ (d & 7);
        bv[df] = *(const bf16x8*)(&Vlds[b][0] + d * 64 + cc * 8);
      }
#pragma unroll
      for (int m = 0; m < 2; ++m) {
        const int q = m * 16 + lr;
        const int pos = (kk * 4 + lg) ^ (q & 7);
        ap[m] = *(const bf16x8*)(Pw + q * 64 + pos * 8);
      }
#pragma unroll
      for (int m = 0; m < 2; ++m)
#pragma unroll
        for (int df = 0; df < 4; ++df)
          oac[m][df] = mfma16(ap[m], bv[df], oac[m][df]);
    }
    __builtin_amdgcn_s_setprio(0);

    asm volatile("s_waitcnt vmcnt(0)" ::: "memory");
    __builtin_amdgcn_s_barrier();
  }
#undef STAGE

  // epilogue: write O fragment-packed (proj-A layout) so gemm_direct<1> streams it
  const int bidx = bh >> 4, h = bh & 15;
  const float l0 = 1.f / lrun[0], l1 = 1.f / lrun[1];
#pragma unroll
  for (int m = 0; m < 2; ++m) {
#pragma unroll
    for (int j = 0; j < 4; ++j) {
      const float fi = __shfl(m ? l1 : l0, lg * 4 + j, 16);
      const int grow = bidx * NSEQ + q0 + wv * 32 + m * 16 + lg * 4 + j;
#pragma unroll
      for (int df = 0; df < 4; ++df) {
        const int col = h * 64 + df * 16 + lr;
        Oat[fa_elem(grow, col)] = f2bf(oac[m][df][j] * fi);
      }
    }
  }
}

// ---------------- launch ----------------
extern "C" void kernel_launch(void* const* d_in, const int* in_sizes, int n_in,
                              void* d_out, int out_size, void* d_ws, size_t ws_size,
                              hipStream_t stream) {
  const float* x      = (const float*)d_in[0];
  const float* prompt = (const float*)d_in[1];
  const float* alpha  = (const float*)d_in[2];
  const float* halfa  = (const float*)d_in[3];
  const float* Wqkv   = (const float*)d_in[4];
  const float* Wproj  = (const float*)d_in[5];
  const float* bproj  = (const float*)d_in[6];
  float* out = (float*)d_out;

  unsigned short* ws    = (unsigned short*)d_ws;
  unsigned short* x_bf  = ws;                                  // frag-packed
  unsigned short* w_bf  = x_bf + (size_t)8192 * 1024;          // frag-packed
  unsigned short* wp_bf = w_bf + (size_t)3072 * 1024;          // frag-packed
  unsigned short* Qg    = wp_bf + (size_t)1024 * 1024;
  unsigned short* Kg    = Qg + (size_t)NB * NH * NSEQ * NHD;
  unsigned short* Vt    = Kg + (size_t)NB * NH * NKV * NHD;
  unsigned short* Oat   = Vt + (size_t)NB * NH * NKV * NHD;    // frag-packed

  pack_fused<<<6656, 256, 0, stream>>>(x, Wqkv, Wproj, prompt, x_bf, w_bf, wp_bf,
                                       Kg, Vt, alpha);

  // QKV: M=8192 N=3072 -> 64 x 24 of 128^2, direct-streaming
  gemm_direct<0><<<dim3(64, 24), 256, 0, stream>>>(x_bf, w_bf, Qg, Kg, Vt, alpha, halfa,
                                                   nullptr, nullptr);
  attn_fwd<<<1024, 256, 0, stream>>>(Qg, Kg, Vt, Oat);
  // proj: M=8192 N=1024 -> 64 x 8 of 128^2, direct-streaming
  gemm_direct<1><<<dim3(64, 8), 256, 0, stream>>>(Oat, wp_bf, nullptr, nullptr, nullptr,
                                                  nullptr, nullptr, out, bproj);
}

// Round 11
// 165.350 us; speedup vs baseline: 1.2079x; 1.0707x over previous
//
#include <hip/hip_runtime.h>

typedef float f32x4 __attribute__((ext_vector_type(4)));
typedef short bf16x8 __attribute__((ext_vector_type(8)));

#define NB 8
#define NH 16
#define NSEQ 1024
#define NP 64
#define NKV 1088
#define NC 1024
#define NHD 64
#define BHSZ 69632  // per-(b,h) K/V fragment-packed size = 1088*64

__device__ __forceinline__ unsigned short f2bf(float f) {
  unsigned int u = __builtin_bit_cast(unsigned int, f);
  u += 0x7fffu + ((u >> 16) & 1u);  // RNE
  return (unsigned short)(u >> 16);
}

__device__ __forceinline__ f32x4 mfma16(bf16x8 a, bf16x8 b, f32x4 c) {
  return __builtin_amdgcn_mfma_f32_16x16x32_bf16(a, b, c, 0, 0, 0);
}

// fragment-packed address (element granularity) for a row-major [R][1024] matrix
// (GEMM A/B operands). row = panel*128 + wr*64 + m*16 + lr ; k = t*64 + kk*32 + lg*8 + e
__device__ __forceinline__ size_t fa_elem(int r, int k) {
  return (size_t)(r >> 7) * 131072 + (size_t)(k >> 6) * 8192 + ((r >> 6) & 1) * 4096 +
         ((k >> 5) & 1) * 2048 + ((r >> 4) & 3) * 512 + (((k >> 3) & 3) * 16 + (r & 15)) * 8 +
         (k & 7);
}

// ---------------- fused pack kernel ----------------
__device__ __forceinline__ void fragpack_chunk(const float* __restrict__ src,
                                               unsigned short* __restrict__ dst, int c) {
  const int lane = c & 63, m = (c >> 6) & 3, kk = (c >> 8) & 1, wr = (c >> 9) & 1,
            t = (c >> 10) & 15, panel = c >> 14;
  const int row = panel * 128 + wr * 64 + m * 16 + (lane & 15);
  const int k = t * 64 + kk * 32 + (lane >> 4) * 8;
  const float* s = src + (size_t)row * 1024 + k;
  const float4 v0 = *(const float4*)s;
  const float4 v1 = *(const float4*)(s + 4);
  ushort4 o0, o1;
  o0.x = f2bf(v0.x); o0.y = f2bf(v0.y); o0.z = f2bf(v0.z); o0.w = f2bf(v0.w);
  o1.x = f2bf(v1.x); o1.y = f2bf(v1.y); o1.z = f2bf(v1.z); o1.w = f2bf(v1.w);
  *(ushort4*)(dst + (size_t)c * 8) = o0;
  *(ushort4*)(dst + (size_t)c * 8 + 4) = o1;
}

__global__ void pack_fused(const float* __restrict__ x, const float* __restrict__ wq,
                           const float* __restrict__ wp, const float* __restrict__ prompt,
                           unsigned short* __restrict__ xd, unsigned short* __restrict__ wqd,
                           unsigned short* __restrict__ wpd, unsigned short* __restrict__ Kf,
                           unsigned short* __restrict__ Vf, const float* __restrict__ alpha) {
  int gid = blockIdx.x * 256 + threadIdx.x;
  if (gid < 1048576) {                       // x: 8192x1024
    fragpack_chunk(x, xd, gid);
  } else if (gid < 1441792) {                // Wqkv: 3072x1024
    fragpack_chunk(wq, wqd, gid - 1048576);
  } else if (gid < 1572864) {                // Wproj: 1024x1024
    fragpack_chunk(wp, wpd, gid - 1441792);
  } else {                                   // prompt prefix (t=0 tiles of K/V frag layout)
    int i = gid - 1572864;                   // 131072
    float a = alpha[0];
    int d4 = i & 15, p = (i >> 4) & 63, h = (i >> 10) & 15, b = i >> 14;
    const int bh = b * 16 + h;
    const int d0 = d4 * 4;
    // K: frag (t=0, mk=p>>4, kk=d0>>5); elem (lg=(d0>>3)&3, lr=p&15, e=d0&7 ..+3)
    const float4 kv4 = *(const float4*)(prompt + ((((size_t)(b * 2 + 0) * NP + p) * NH + h) * NHD + d0));
    {
      const int mk = p >> 4, lrk = p & 15, kk = d0 >> 5, lg = (d0 >> 3) & 3, e0 = d0 & 7;
      unsigned short* kd = Kf + (size_t)bh * BHSZ + ((mk * 2 + kk) * 4 + lg) * 128 + lrk * 8 + e0;
      kd[0] = f2bf(kv4.x * a); kd[1] = f2bf(kv4.y * a);
      kd[2] = f2bf(kv4.z * a); kd[3] = f2bf(kv4.w * a);
    }
    // V^T: frag (t=0, df=d0>>4, kk=p>>5); elem (lg=(p>>3)&3, lr=d&15, e=p&7)
    const float4 vv4 = *(const float4*)(prompt + ((((size_t)(b * 2 + 1) * NP + p) * NH + h) * NHD + d0));
    {
      const int df = d0 >> 4, kk = p >> 5, lg = (p >> 3) & 3, e = p & 7;
      unsigned short* vd = Vf + (size_t)bh * BHSZ + ((df * 2 + kk) * 4 + lg) * 128 + e;
      vd[((d0 + 0) & 15) * 8] = f2bf(vv4.x * a);
      vd[((d0 + 1) & 15) * 8] = f2bf(vv4.y * a);
      vd[((d0 + 2) & 15) * 8] = f2bf(vv4.z * a);
      vd[((d0 + 3) & 15) * 8] = f2bf(vv4.w * a);
    }
  }
}

// ---------------- direct-streaming GEMM (no LDS, no barriers, pinned prefetch) --------
// out[m,c] = sum_k A[m,k]*Bw[c,k]; operands fragment-packed. sched_barrier(0) pins the
// t+1 load block above the t MFMA cluster -> 16 loads stay in flight across the MFMAs.
// MODE 0: QKV epilogue (Q row-major; K/V^T attention-frag-packed). MODE 1: f32 + bias.
template <int MODE>
__global__ __launch_bounds__(256, 2)
void gemm_direct(const unsigned short* __restrict__ Af, const unsigned short* __restrict__ Bf,
                 unsigned short* __restrict__ Qg, unsigned short* __restrict__ Kf,
                 unsigned short* __restrict__ Vf,
                 const float* __restrict__ alphap, const float* __restrict__ halfp,
                 float* __restrict__ Cout, const float* __restrict__ bias) {
  const int tid = threadIdx.x, lane = tid & 63, wv = tid >> 6;
  const int wr = wv >> 1, wc = wv & 1;
  const int lg = lane >> 4, lr = lane & 15;
  const int bx = blockIdx.x, by = blockIdx.y;

  const unsigned short* Ab = Af + (size_t)bx * 131072 + wr * 4096 + lane * 8;
  const unsigned short* Bb = Bf + (size_t)by * 131072 + wc * 4096 + lane * 8;

  f32x4 acc[4][4] = {};
  bf16x8 aC[2][4], bC[2][4], aN[2][4], bN[2][4];

#define LOADA(dst, t)                                                          \
  _Pragma("unroll") for (int kk = 0; kk < 2; ++kk)                             \
  _Pragma("unroll") for (int m = 0; m < 4; ++m)                                \
      dst[kk][m] = *(const bf16x8*)(Ab + (size_t)(t) * 8192 + kk * 2048 + m * 512)
#define LOADB(dst, t)                                                          \
  _Pragma("unroll") for (int kk = 0; kk < 2; ++kk)                             \
  _Pragma("unroll") for (int n = 0; n < 4; ++n)                                \
      dst[kk][n] = *(const bf16x8*)(Bb + (size_t)(t) * 8192 + kk * 2048 + n * 512)

  LOADA(aC, 0);
  LOADB(bC, 0);
#pragma unroll
  for (int t = 0; t < 16; ++t) {
    if (t < 15) { LOADA(aN, t + 1); LOADB(bN, t + 1); }
    __builtin_amdgcn_sched_barrier(0);  // pin prefetch above the MFMA cluster
    __builtin_amdgcn_s_setprio(1);
#pragma unroll
    for (int kk = 0; kk < 2; ++kk)
#pragma unroll
      for (int m = 0; m < 4; ++m)
#pragma unroll
        for (int n = 0; n < 4; ++n)
          acc[m][n] = mfma16(aC[kk][m], bC[kk][n], acc[m][n]);
    __builtin_amdgcn_s_setprio(0);
#pragma unroll
    for (int kk = 0; kk < 2; ++kk)
#pragma unroll
      for (int i = 0; i < 4; ++i) { aC[kk][i] = aN[kk][i]; bC[kk][i] = bN[kk][i]; }
  }
#undef LOADA
#undef LOADB

  if constexpr (MODE == 0) {
    const int slot = (by * 128) >> 10;
    const int csIn = (by * 128) & 1023;
    // Q gets softmax scale folded in base-2 domain: 0.125 * log2(e)
    const float sc = (slot == 0) ? 0.18033688011112042f : (alphap[0] * halfp[0]);
#pragma unroll
    for (int m = 0; m < 4; ++m) {
      const int grow0 = bx * 128 + wr * 64 + m * 16 + lg * 4;
#pragma unroll
      for (int n = 0; n < 4; ++n) {
        const int gcol = csIn + wc * 64 + n * 16 + lr;
        const int h = gcol >> 6, d = gcol & 63;
#pragma unroll
        for (int j = 0; j < 4; ++j) {
          const int grow = grow0 + j;
          const int b = grow >> 10, nn = grow & 1023;
          const int bh = b * 16 + h;
          const unsigned short u = f2bf(acc[m][n][j] * sc);
          if (slot == 0) {
            Qg[((size_t)bh * NSEQ + nn) * NHD + d] = u;
          } else if (slot == 1) {
            const int kv = NP + nn;
            const int t = kv >> 6, mk = (kv >> 4) & 3, lrk = kv & 15;
            const int kkk = d >> 5, lgk = (d >> 3) & 3, e = d & 7;
            Kf[(size_t)bh * BHSZ + (size_t)((t * 4 + mk) * 2 + kkk) * 512 + (lgk * 16 + lrk) * 8 + e] = u;
          } else {
            const int kv = NP + nn;
            const int t = kv >> 6, kkv = (kv >> 5) & 1, lgv = (kv >> 3) & 3, e = kv & 7;
            const int df = d >> 4, lrv = d & 15;
            Vf[(size_t)bh * BHSZ + (size_t)((t * 4 + df) * 2 + kkv) * 512 + (lgv * 16 + lrv) * 8 + e] = u;
          }
        }
      }
    }
  } else {
#pragma unroll
    for (int m = 0; m < 4; ++m) {
      const int grow0 = bx * 128 + wr * 64 + m * 16 + lg * 4;
#pragma unroll
      for (int n = 0; n < 4; ++n) {
        const int gcol = by * 128 + wc * 64 + n * 16 + lr;
        const float bb = bias[gcol];
#pragma unroll
        for (int j = 0; j < 4; ++j)
          Cout[(size_t)(grow0 + j) * NC + gcol] = acc[m][n][j] + bb;
      }
    }
  }
}

// ---------------- flash attention: barrier-free, frag-direct K/V streaming ----------
// 4 waves x 32 q-rows, fully independent (no __syncthreads, no vmcnt drains).
// K/V^T read as contiguous 1KB fragment loads from global (L2-served).
__global__ __launch_bounds__(256, 3)
void attn_fwd(const unsigned short* __restrict__ Qg, const unsigned short* __restrict__ Kf,
              const unsigned short* __restrict__ Vf, unsigned short* __restrict__ Oat) {
  __shared__ __align__(16) unsigned short Plds[4 * 32 * 64];
  const int tid = threadIdx.x, lane = tid & 63, wv = tid >> 6;
  const int bh = blockIdx.x & 127;
  const int q0 = (blockIdx.x >> 7) * 128;
  const int lg = lane >> 4, lr = lane & 15;

  bf16x8 bq[2][2];
#pragma unroll
  for (int nq = 0; nq < 2; ++nq)
#pragma unroll
    for (int kk = 0; kk < 2; ++kk)
      bq[nq][kk] = *(const bf16x8*)(Qg + ((size_t)bh * NSEQ + q0 + wv * 32 + nq * 16 + lr) * NHD + kk * 32 + lg * 8);

  f32x4 oac[2][4] = {};
  float mrun[2] = {-1e30f, -1e30f};
  float lrun[2] = {0.f, 0.f};

  const unsigned short* Kb = Kf + (size_t)bh * BHSZ + lane * 8;
  const unsigned short* Vb = Vf + (size_t)bh * BHSZ + lane * 8;
  unsigned short* Pw = Plds + wv * 2048;

  for (int t = 0; t < 17; ++t) {
    // load K frags for this tile (8 x 1KB coalesced)
    bf16x8 ak[4][2];
#pragma unroll
    for (int mk = 0; mk < 4; ++mk)
#pragma unroll
      for (int kk = 0; kk < 2; ++kk)
        ak[mk][kk] = *(const bf16x8*)(Kb + (size_t)((t * 4 + mk) * 2 + kk) * 512);

    f32x4 sa[4][2] = {};
    __builtin_amdgcn_s_setprio(1);
#pragma unroll
    for (int kk = 0; kk < 2; ++kk)
#pragma unroll
      for (int mk = 0; mk < 4; ++mk)
#pragma unroll
        for (int nq = 0; nq < 2; ++nq)
          sa[mk][nq] = mfma16(ak[mk][kk], bq[nq][kk], sa[mk][nq]);
    __builtin_amdgcn_s_setprio(0);

    // issue V loads now; softmax VALU below hides their latency
    bf16x8 bv[4][2];
#pragma unroll
    for (int df = 0; df < 4; ++df)
#pragma unroll
      for (int kk = 0; kk < 2; ++kk)
        bv[df][kk] = *(const bf16x8*)(Vb + (size_t)((t * 4 + df) * 2 + kk) * 512);

    float tmx[2];
#pragma unroll
    for (int nq = 0; nq < 2; ++nq) {
      f32x4 m4 = sa[0][nq];
#pragma unroll
      for (int mk = 1; mk < 4; ++mk)
#pragma unroll
        for (int j = 0; j < 4; ++j) m4[j] = fmaxf(m4[j], sa[mk][nq][j]);
      float tm = fmaxf(fmaxf(m4[0], m4[1]), fmaxf(m4[2], m4[3]));
      tm = fmaxf(tm, __shfl_xor(tm, 16));
      tm = fmaxf(tm, __shfl_xor(tm, 32));
      tmx[nq] = tm;
    }
    const bool upd = !__all((tmx[0] <= mrun[0] + 8.f) && (tmx[1] <= mrun[1] + 8.f));
    if (upd) {
      const float nm0 = fmaxf(mrun[0], tmx[0]);
      const float nm1 = fmaxf(mrun[1], tmx[1]);
      const float e0 = __builtin_amdgcn_exp2f(mrun[0] - nm0);
      const float e1 = __builtin_amdgcn_exp2f(mrun[1] - nm1);
      mrun[0] = nm0; mrun[1] = nm1;
      lrun[0] *= e0; lrun[1] *= e1;
#pragma unroll
      for (int m = 0; m < 2; ++m)
#pragma unroll
        for (int j = 0; j < 4; ++j) {
          const float fe = __shfl(m ? e1 : e0, lg * 4 + j, 16);
#pragma unroll
          for (int df = 0; df < 4; ++df) oac[m][df][j] *= fe;
        }
    }
#pragma unroll
    for (int nq = 0; nq < 2; ++nq) {
#pragma unroll
      for (int mk = 0; mk < 4; ++mk)
#pragma unroll
        for (int j = 0; j < 4; ++j)
          sa[mk][nq][j] = __builtin_amdgcn_exp2f(sa[mk][nq][j] - mrun[nq]);
      f32x4 s4 = sa[0][nq];
#pragma unroll
      for (int mk = 1; mk < 4; ++mk)
#pragma unroll
        for (int j = 0; j < 4; ++j) s4[j] += sa[mk][nq][j];
      float s = (s4[0] + s4[1]) + (s4[2] + s4[3]);
      s += __shfl_xor(s, 16);
      s += __shfl_xor(s, 32);
      lrun[nq] += s;
      const int q = nq * 16 + lr;
#pragma unroll
      for (int mk = 0; mk < 4; ++mk) {
        const int c = mk * 2 + (lg >> 1);
        uint2 uu;
        uu.x = (unsigned)f2bf(sa[mk][nq][0]) | ((unsigned)f2bf(sa[mk][nq][1]) << 16);
        uu.y = (unsigned)f2bf(sa[mk][nq][2]) | ((unsigned)f2bf(sa[mk][nq][3]) << 16);
        *(uint2*)(Pw + q * 64 + ((c ^ (q & 7)) << 3) + (lg & 1) * 4) = uu;
      }
    }

    __builtin_amdgcn_s_setprio(1);
#pragma unroll
    for (int kk = 0; kk < 2; ++kk) {
      bf16x8 ap[2];
#pragma unroll
      for (int m = 0; m < 2; ++m) {
        const int q = m * 16 + lr;
        const int pos = (kk * 4 + lg) ^ (q & 7);
        ap[m] = *(const bf16x8*)(Pw + q * 64 + pos * 8);
      }
#pragma unroll
      for (int m = 0; m < 2; ++m)
#pragma unroll
        for (int df = 0; df < 4; ++df)
          oac[m][df] = mfma16(ap[m], bv[df][kk], oac[m][df]);
    }
    __builtin_amdgcn_s_setprio(0);
  }

  // epilogue: write O fragment-packed (proj-A layout) so gemm_direct<1> streams it
  const int bidx = bh >> 4, h = bh & 15;
  const float l0 = 1.f / lrun[0], l1 = 1.f / lrun[1];
#pragma unroll
  for (int m = 0; m < 2; ++m) {
#pragma unroll
    for (int j = 0; j < 4; ++j) {
      const float fi = __shfl(m ? l1 : l0, lg * 4 + j, 16);
      const int grow = bidx * NSEQ + q0 + wv * 32 + m * 16 + lg * 4 + j;
#pragma unroll
      for (int df = 0; df < 4; ++df) {
        const int col = h * 64 + df * 16 + lr;
        Oat[fa_elem(grow, col)] = f2bf(oac[m][df][j] * fi);
      }
    }
  }
}

// ---------------- launch ----------------
extern "C" void kernel_launch(void* const* d_in, const int* in_sizes, int n_in,
                              void* d_out, int out_size, void* d_ws, size_t ws_size,
                              hipStream_t stream) {
  const float* x      = (const float*)d_in[0];
  const float* prompt = (const float*)d_in[1];
  const float* alpha  = (const float*)d_in[2];
  const float* halfa  = (const float*)d_in[3];
  const float* Wqkv   = (const float*)d_in[4];
  const float* Wproj  = (const float*)d_in[5];
  const float* bproj  = (const float*)d_in[6];
  float* out = (float*)d_out;

  unsigned short* ws    = (unsigned short*)d_ws;
  unsigned short* x_bf  = ws;                                  // frag-packed
  unsigned short* w_bf  = x_bf + (size_t)8192 * 1024;          // frag-packed
  unsigned short* wp_bf = w_bf + (size_t)3072 * 1024;          // frag-packed
  unsigned short* Qg    = wp_bf + (size_t)1024 * 1024;         // row-major
  unsigned short* Kf    = Qg + (size_t)NB * NH * NSEQ * NHD;   // attn-frag-packed
  unsigned short* Vf    = Kf + (size_t)128 * BHSZ;             // attn-frag-packed
  unsigned short* Oat   = Vf + (size_t)128 * BHSZ;             // frag-packed

  pack_fused<<<6656, 256, 0, stream>>>(x, Wqkv, Wproj, prompt, x_bf, w_bf, wp_bf,
                                       Kf, Vf, alpha);

  // QKV: M=8192 N=3072 -> 64 x 24 of 128^2, direct-streaming
  gemm_direct<0><<<dim3(64, 24), 256, 0, stream>>>(x_bf, w_bf, Qg, Kf, Vf, alpha, halfa,
                                                   nullptr, nullptr);
  attn_fwd<<<1024, 256, 0, stream>>>(Qg, Kf, Vf, Oat);
  // proj: M=8192 N=1024 -> 64 x 8 of 128^2, direct-streaming
  gemm_direct<1><<<dim3(64, 8), 256, 0, stream>>>(Oat, wp_bf, nullptr, nullptr, nullptr,
                                                  nullptr, nullptr, out, bproj);
}